// Round 1
// baseline (2367.753 us; speedup 1.0000x reference)
//
#include <hip/hip_runtime.h>
#include <cstddef>

#define NEG_SLOPE 0.2f
#define LN_EPS 1e-5f

// ---------------------------------------------------------------------------
// Kernel 1: h = x @ W_gat  (N x 128 @ 128 x 128), plus per-head attention
// logits a_s[n,h] = sum_c h[n,h,c]*att_src[h,c], a_d likewise.
// Block: 256 threads, 32 rows/block. W_gat (64KB) + x rows (16KB) in LDS.
// Thread = (colg = tid&31 -> 4 cols, rs = tid>>5 -> 4 rows stride 8).
// ---------------------------------------------------------------------------
__global__ __launch_bounds__(256) void k_gat_proj(
    const float* __restrict__ x, const float* __restrict__ Wg,
    const float* __restrict__ atts, const float* __restrict__ attd,
    float* __restrict__ h, float* __restrict__ a_s, float* __restrict__ a_d,
    int nn)
{
    __shared__ float sW[128 * 128];     // [k][j], 64 KB
    __shared__ float sx[32][128];       // 16 KB
    __shared__ float4 sas[32], sad[32];

    const int tid = threadIdx.x;
    const int base = blockIdx.x * 32;

    for (int i = tid; i < 4096; i += 256)
        ((float4*)sW)[i] = ((const float4*)Wg)[i];
    if (tid < 32) { sas[tid] = ((const float4*)atts)[tid]; sad[tid] = ((const float4*)attd)[tid]; }
    // load 32 rows of x (zero-fill OOB rows to avoid NaN garbage)
    for (int i = tid; i < 1024; i += 256) {
        int row = i >> 5;
        float4 v = make_float4(0.f, 0.f, 0.f, 0.f);
        if (base + row < nn) v = ((const float4*)(x + (size_t)(base + row) * 128))[i & 31];
        ((float4*)sx)[i] = v;
    }
    __syncthreads();

    const int colg = tid & 31;  // 4-column group: cols 4*colg..4*colg+3
    const int rs   = tid >> 5;  // row slot 0..7

    float4 acc[4];
    #pragma unroll
    for (int r = 0; r < 4; ++r) acc[r] = make_float4(0.f, 0.f, 0.f, 0.f);

    #pragma unroll 4
    for (int k = 0; k < 128; ++k) {
        float4 wv = ((const float4*)(sW + k * 128))[colg];
        #pragma unroll
        for (int r = 0; r < 4; ++r) {
            float xv = sx[rs + 8 * r][k];
            acc[r].x += xv * wv.x; acc[r].y += xv * wv.y;
            acc[r].z += xv * wv.z; acc[r].w += xv * wv.w;
        }
    }

    float4 as4 = sas[colg], ad4 = sad[colg];
    #pragma unroll
    for (int r = 0; r < 4; ++r) {
        int n = base + rs + 8 * r;
        float ps = acc[r].x * as4.x + acc[r].y * as4.y + acc[r].z * as4.z + acc[r].w * as4.w;
        float pd = acc[r].x * ad4.x + acc[r].y * ad4.y + acc[r].z * ad4.z + acc[r].w * ad4.w;
        // reduce over the 4 lanes covering one head (16 channels)
        ps += __shfl_xor(ps, 1, 4); ps += __shfl_xor(ps, 2, 4);
        pd += __shfl_xor(pd, 1, 4); pd += __shfl_xor(pd, 2, 4);
        if (n < nn) {
            ((float4*)(h + (size_t)n * 128))[colg] = acc[r];
            if ((colg & 3) == 0) {
                int head = colg >> 2;
                a_s[(size_t)n * 8 + head] = ps;
                a_d[(size_t)n * 8 + head] = pd;
            }
        }
    }
}

// ---------------------------------------------------------------------------
// Kernel 2: edge pass. Half-wave (32 lanes) per edge; lane l covers channels
// 4l..4l+3 (head = l>>2). w = exp(leakyrelu(a_s[src]+a_d[dst])).
// Unnormalized accumulate: S[dst] += w*h[src]; den[dst,head] += w.
// (segment softmax is shift-invariant; logits are O(1) so no max needed)
// ---------------------------------------------------------------------------
__global__ __launch_bounds__(256) void k_edge(
    const int* __restrict__ ei, const float* __restrict__ h,
    const float* __restrict__ a_s, const float* __restrict__ a_d,
    float* __restrict__ S, float* __restrict__ den, int E)
{
    int t = blockIdx.x * 256 + threadIdx.x;
    int eid = t >> 5;
    if (eid >= E) return;
    int l = threadIdx.x & 31;
    int src = ei[eid];
    int dst = ei[(size_t)E + eid];
    int head = l >> 2;
    float e = a_s[(size_t)src * 8 + head] + a_d[(size_t)dst * 8 + head];
    e = (e >= 0.f) ? e : NEG_SLOPE * e;
    float w = expf(e);
    float4 hv = *(const float4*)(h + (size_t)src * 128 + 4 * l);
    float* Sp = S + (size_t)dst * 128 + 4 * l;
    unsafeAtomicAdd(Sp + 0, w * hv.x);
    unsafeAtomicAdd(Sp + 1, w * hv.y);
    unsafeAtomicAdd(Sp + 2, w * hv.z);
    unsafeAtomicAdd(Sp + 3, w * hv.w);
    if ((l & 3) == 0) unsafeAtomicAdd(&den[(size_t)dst * 8 + head], w);
}

// ---------------------------------------------------------------------------
// Kernel 3: node pass. Wave per node. Adds self-loop contribution
// analytically, normalizes, residual + LayerNorm1. Writes h1 IN PLACE over S
// (each lane reads exactly the 2 floats it overwrites; reductions are
// register shuffles, so aliasing is safe).
// ---------------------------------------------------------------------------
__global__ __launch_bounds__(256) void k_node(
    const float* __restrict__ x, const float* __restrict__ h,
    const float* __restrict__ a_s, const float* __restrict__ a_d,
    float* Sh1 /* in: S, out: h1 (aliased) */, const float* __restrict__ den,
    const float* __restrict__ bgat, const float* __restrict__ g1,
    const float* __restrict__ b1, int nn)
{
    int n = (blockIdx.x * 256 + threadIdx.x) >> 6;
    if (n >= nn) return;
    int lane = threadIdx.x & 63;
    int head = lane >> 3;  // channels 2*lane, 2*lane+1 -> head = lane/8

    float e = a_s[(size_t)n * 8 + head] + a_d[(size_t)n * 8 + head];
    e = (e >= 0.f) ? e : NEG_SLOPE * e;
    float wself = expf(e);
    float inv_dn = 1.f / (den[(size_t)n * 8 + head] + wself);

    float2 Sv = *(const float2*)(Sh1 + (size_t)n * 128 + 2 * lane);
    float2 hv = *(const float2*)(h + (size_t)n * 128 + 2 * lane);
    float2 xv = *(const float2*)(x + (size_t)n * 128 + 2 * lane);
    float2 bg = *(const float2*)(bgat + 2 * lane);

    float v0 = xv.x + (Sv.x + wself * hv.x) * inv_dn + bg.x;
    float v1 = xv.y + (Sv.y + wself * hv.y) * inv_dn + bg.y;

    float s = v0 + v1;
    #pragma unroll
    for (int off = 32; off; off >>= 1) s += __shfl_xor(s, off, 64);
    float mu = s * (1.f / 128.f);
    float d0 = v0 - mu, d1 = v1 - mu;
    float q = d0 * d0 + d1 * d1;
    #pragma unroll
    for (int off = 32; off; off >>= 1) q += __shfl_xor(q, off, 64);
    float inv = rsqrtf(q * (1.f / 128.f) + LN_EPS);

    float2 gv = ((const float2*)g1)[lane];
    float2 bv = ((const float2*)b1)[lane];
    float2 o;
    o.x = d0 * inv * gv.x + bv.x;
    o.y = d1 * inv * gv.y + bv.y;
    *(float2*)(Sh1 + (size_t)n * 128 + 2 * lane) = o;
}

// ---------------------------------------------------------------------------
// Kernel 4: FF block, fused per 32-node tile:
//   t = relu(h1@W1 + b1) (kept in LDS), y = t@W2 + b2,
//   out = LN2(h1 + y).
// LDS: sh1 32x128 (16KB) + st 32x512 (64KB).
// ---------------------------------------------------------------------------
#define BN 32
__global__ __launch_bounds__(256) void k_ff(
    const float* __restrict__ h1g, const float* __restrict__ W1,
    const float* __restrict__ b1, const float* __restrict__ W2,
    const float* __restrict__ b2, const float* __restrict__ g2,
    const float* __restrict__ bln2, float* __restrict__ out, int nn)
{
    __shared__ float sh1[BN][128];
    __shared__ float st[BN][512];
    const int tid = threadIdx.x;
    const int base = blockIdx.x * BN;

    for (int i = tid; i < BN * 32; i += 256) {
        int row = i >> 5;
        float4 v = make_float4(0.f, 0.f, 0.f, 0.f);
        if (base + row < nn) v = ((const float4*)(h1g + (size_t)(base + row) * 128))[i & 31];
        ((float4*)sh1)[i] = v;
    }
    __syncthreads();

    // phase 2: hidden = relu(h1@W1 + b1). thread owns cols j0=tid, j1=tid+256.
    {
        const int j0 = tid, j1 = tid + 256;
        float acc0[BN], acc1[BN];
        float bb0 = b1[j0], bb1 = b1[j1];
        #pragma unroll
        for (int n = 0; n < BN; ++n) { acc0[n] = bb0; acc1[n] = bb1; }
        for (int k4 = 0; k4 < 32; ++k4) {
            float w0[4], w1[4];
            #pragma unroll
            for (int i = 0; i < 4; ++i) {
                w0[i] = W1[(size_t)(k4 * 4 + i) * 512 + j0];
                w1[i] = W1[(size_t)(k4 * 4 + i) * 512 + j1];
            }
            #pragma unroll
            for (int n = 0; n < BN; ++n) {
                float4 xv = *(const float4*)&sh1[n][k4 * 4];
                acc0[n] += xv.x * w0[0] + xv.y * w0[1] + xv.z * w0[2] + xv.w * w0[3];
                acc1[n] += xv.x * w1[0] + xv.y * w1[1] + xv.z * w1[2] + xv.w * w1[3];
            }
        }
        #pragma unroll
        for (int n = 0; n < BN; ++n) {
            st[n][j0] = fmaxf(acc0[n], 0.f);
            st[n][j1] = fmaxf(acc1[n], 0.f);
        }
    }
    __syncthreads();

    // phase 3: y = t@W2 + b2. thread: col jj=tid&127, nodes (tid>>7)*16..+15
    {
        const int jj = tid & 127, half = tid >> 7;
        float acc[16];
        float bb = b2[jj];
        #pragma unroll
        for (int n = 0; n < 16; ++n) acc[n] = bb;
        for (int k4 = 0; k4 < 128; ++k4) {
            float w[4];
            #pragma unroll
            for (int i = 0; i < 4; ++i) w[i] = W2[(size_t)(k4 * 4 + i) * 128 + jj];
            #pragma unroll
            for (int n = 0; n < 16; ++n) {
                float4 tv = *(const float4*)&st[half * 16 + n][k4 * 4];
                acc[n] += tv.x * w[0] + tv.y * w[1] + tv.z * w[2] + tv.w * w[3];
            }
        }
        __syncthreads();  // everyone done READING st before we overwrite it
        float* sv = &st[0][0];  // reuse as [32][128] v = h1 + y
        #pragma unroll
        for (int n = 0; n < 16; ++n)
            sv[(size_t)(half * 16 + n) * 128 + jj] = acc[n] + sh1[half * 16 + n][jj];
    }
    __syncthreads();

    // phase 4: LN2 per node; wave per node (4 waves x 8 nodes)
    {
        const int wv = tid >> 6, lane = tid & 63;
        const float* sv = &st[0][0];
        float2 gv = ((const float2*)g2)[lane];
        float2 bv = ((const float2*)bln2)[lane];
        for (int r = 0; r < 8; ++r) {
            int n = wv * 8 + r;
            if (base + n >= nn) break;
            float v0 = sv[(size_t)n * 128 + 2 * lane];
            float v1 = sv[(size_t)n * 128 + 2 * lane + 1];
            float s = v0 + v1;
            #pragma unroll
            for (int off = 32; off; off >>= 1) s += __shfl_xor(s, off, 64);
            float mu = s * (1.f / 128.f);
            float d0 = v0 - mu, d1 = v1 - mu;
            float q = d0 * d0 + d1 * d1;
            #pragma unroll
            for (int off = 32; off; off >>= 1) q += __shfl_xor(q, off, 64);
            float inv = rsqrtf(q * (1.f / 128.f) + LN_EPS);
            float2 o;
            o.x = d0 * inv * gv.x + bv.x;
            o.y = d1 * inv * gv.y + bv.y;
            ((float2*)(out + (size_t)(base + n) * 128))[lane] = o;
        }
    }
}

// ---------------------------------------------------------------------------
extern "C" void kernel_launch(void* const* d_in, const int* in_sizes, int n_in,
                              void* d_out, int out_size, void* d_ws, size_t ws_size,
                              hipStream_t stream) {
    const float* x    = (const float*)d_in[0];
    const int*   ei   = (const int*)d_in[1];
    const float* Wg   = (const float*)d_in[2];
    const float* atts = (const float*)d_in[3];
    const float* attd = (const float*)d_in[4];
    const float* bgat = (const float*)d_in[5];
    const float* W1   = (const float*)d_in[6];
    const float* b1   = (const float*)d_in[7];
    const float* W2   = (const float*)d_in[8];
    const float* b2   = (const float*)d_in[9];
    const float* g1   = (const float*)d_in[10];
    const float* bln1 = (const float*)d_in[11];
    const float* g2   = (const float*)d_in[12];
    const float* bln2 = (const float*)d_in[13];
    float* out = (float*)d_out;

    const int nn = in_sizes[0] / 128;
    const int E  = in_sizes[1] / 2;

    // workspace layout (floats): h | a_s | a_d | S(->h1) | den   = n*(128+8+8+128+8)
    float* ws  = (float*)d_ws;
    float* h   = ws;
    float* a_s = h + (size_t)nn * 128;
    float* a_d = a_s + (size_t)nn * 8;
    float* S   = a_d + (size_t)nn * 8;   // aliased as h1 after k_node
    float* den = S + (size_t)nn * 128;

    // zero S + den (contiguous: nn*136 floats)
    hipMemsetAsync(S, 0, (size_t)nn * 136 * sizeof(float), stream);

    k_gat_proj<<<dim3((nn + 31) / 32), dim3(256), 0, stream>>>(x, Wg, atts, attd, h, a_s, a_d, nn);
    k_edge<<<dim3((E + 7) / 8), dim3(256), 0, stream>>>(ei, h, a_s, a_d, S, den, E);
    k_node<<<dim3((nn + 3) / 4), dim3(256), 0, stream>>>(x, h, a_s, a_d, S, den, bgat, g1, bln1, nn);
    k_ff<<<dim3((nn + BN - 1) / BN), dim3(256), 0, stream>>>(S, W1, b1, W2, b2, g2, bln2, out, nn);
}

// Round 2
// 1212.888 us; speedup vs baseline: 1.9522x; 1.9522x over previous
//
#include <hip/hip_runtime.h>
#include <cstddef>

#define NEG_SLOPE 0.2f
#define LN_EPS 1e-5f

// ---------------------------------------------------------------------------
// Kernel 1: h = x @ W_gat  (N x 128 @ 128 x 128), plus per-head attention
// logits a_s[n,h] = sum_c h[n,h,c]*att_src[h,c], a_d likewise.
// ---------------------------------------------------------------------------
__global__ __launch_bounds__(256) void k_gat_proj(
    const float* __restrict__ x, const float* __restrict__ Wg,
    const float* __restrict__ atts, const float* __restrict__ attd,
    float* __restrict__ h, float* __restrict__ a_s, float* __restrict__ a_d,
    int nn)
{
    __shared__ float sW[128 * 128];     // [k][j], 64 KB
    __shared__ float sx[32][128];       // 16 KB
    __shared__ float4 sas[32], sad[32];

    const int tid = threadIdx.x;
    const int base = blockIdx.x * 32;

    for (int i = tid; i < 4096; i += 256)
        ((float4*)sW)[i] = ((const float4*)Wg)[i];
    if (tid < 32) { sas[tid] = ((const float4*)atts)[tid]; sad[tid] = ((const float4*)attd)[tid]; }
    for (int i = tid; i < 1024; i += 256) {
        int row = i >> 5;
        float4 v = make_float4(0.f, 0.f, 0.f, 0.f);
        if (base + row < nn) v = ((const float4*)(x + (size_t)(base + row) * 128))[i & 31];
        ((float4*)sx)[i] = v;
    }
    __syncthreads();

    const int colg = tid & 31;  // 4-column group: cols 4*colg..4*colg+3
    const int rs   = tid >> 5;  // row slot 0..7

    float4 acc[4];
    #pragma unroll
    for (int r = 0; r < 4; ++r) acc[r] = make_float4(0.f, 0.f, 0.f, 0.f);

    #pragma unroll 4
    for (int k = 0; k < 128; ++k) {
        float4 wv = ((const float4*)(sW + k * 128))[colg];
        #pragma unroll
        for (int r = 0; r < 4; ++r) {
            float xv = sx[rs + 8 * r][k];
            acc[r].x += xv * wv.x; acc[r].y += xv * wv.y;
            acc[r].z += xv * wv.z; acc[r].w += xv * wv.w;
        }
    }

    float4 as4 = sas[colg], ad4 = sad[colg];
    #pragma unroll
    for (int r = 0; r < 4; ++r) {
        int n = base + rs + 8 * r;
        float ps = acc[r].x * as4.x + acc[r].y * as4.y + acc[r].z * as4.z + acc[r].w * as4.w;
        float pd = acc[r].x * ad4.x + acc[r].y * ad4.y + acc[r].z * ad4.z + acc[r].w * ad4.w;
        ps += __shfl_xor(ps, 1, 4); ps += __shfl_xor(ps, 2, 4);
        pd += __shfl_xor(pd, 1, 4); pd += __shfl_xor(pd, 2, 4);
        if (n < nn) {
            ((float4*)(h + (size_t)n * 128))[colg] = acc[r];
            if ((colg & 3) == 0) {
                int head = colg >> 2;
                a_s[(size_t)n * 8 + head] = ps;
                a_d[(size_t)n * 8 + head] = pd;
            }
        }
    }
}

// ---------------------------------------------------------------------------
// CSR binning: degree histogram -> exclusive scan -> scatter src ids.
// After k_scatter, ptr[d] == end(d); start(d) = (d==0) ? 0 : ptr[d-1].
// ---------------------------------------------------------------------------
__global__ __launch_bounds__(256) void k_deg(
    const int* __restrict__ ei, int* __restrict__ deg, int E)
{
    int e = blockIdx.x * 256 + threadIdx.x;
    if (e < E) atomicAdd(&deg[ei[(size_t)E + e]], 1);
}

__global__ __launch_bounds__(1024) void k_scan(int* __restrict__ ptr, int nn)
{
    __shared__ int part[1024];
    const int tid = threadIdx.x;
    const int chunk = (nn + 1023) >> 10;
    const int lo = tid * chunk;
    const int hi = min(lo + chunk, nn);
    int s = 0;
    for (int i = lo; i < hi; ++i) s += ptr[i];
    part[tid] = s;
    __syncthreads();
    for (int d = 1; d < 1024; d <<= 1) {
        int add = (tid >= d) ? part[tid - d] : 0;
        __syncthreads();
        part[tid] += add;
        __syncthreads();
    }
    int off = (tid == 0) ? 0 : part[tid - 1];
    for (int i = lo; i < hi; ++i) { int v = ptr[i]; ptr[i] = off; off += v; }
}

__global__ __launch_bounds__(256) void k_scatter(
    const int* __restrict__ ei, int* __restrict__ ptr,
    int* __restrict__ esrc, int E)
{
    int e = blockIdx.x * 256 + threadIdx.x;
    if (e < E) {
        int pos = atomicAdd(&ptr[ei[(size_t)E + e]], 1);
        esrc[pos] = ei[e];
    }
}

// ---------------------------------------------------------------------------
// Kernel 5: gather + softmax-normalize + self-loop + residual + LN1, fused.
// Half-wave (32 lanes) per destination node; lane l owns channels 4l..4l+3
// (head = l>>2). No float atomics anywhere. h rows are LLC-resident (51 MB).
// Writes h1 into d_out (k_ff reads its tile before overwriting it).
// ---------------------------------------------------------------------------
__global__ __launch_bounds__(256) void k_gather(
    const int* __restrict__ esrc, const int* __restrict__ ptr,
    const float* __restrict__ h, const float* __restrict__ a_s,
    const float* __restrict__ a_d, const float* __restrict__ x,
    const float* __restrict__ bgat, const float* __restrict__ g1,
    const float* __restrict__ b1, float* __restrict__ h1, int nn)
{
    int d = (blockIdx.x * 256 + threadIdx.x) >> 5;
    if (d >= nn) return;
    const int l = threadIdx.x & 31;
    const int head = l >> 2;

    const int start = (d == 0) ? 0 : ptr[d - 1];
    const int end = ptr[d];
    const float ad = a_d[(size_t)d * 8 + head];

    float4 acc = make_float4(0.f, 0.f, 0.f, 0.f);
    float wsum = 0.f;
    for (int e = start; e < end; ++e) {
        int s = esrc[e];  // same addr across half-wave -> broadcast
        float lg = a_s[(size_t)s * 8 + head] + ad;
        lg = (lg >= 0.f) ? lg : NEG_SLOPE * lg;
        float w = expf(lg);
        float4 hv = *(const float4*)(h + (size_t)s * 128 + 4 * l);
        acc.x += w * hv.x; acc.y += w * hv.y;
        acc.z += w * hv.z; acc.w += w * hv.w;
        wsum += w;
    }
    // self loop (added analytically, never materialized as an edge)
    {
        float lg = a_s[(size_t)d * 8 + head] + ad;
        lg = (lg >= 0.f) ? lg : NEG_SLOPE * lg;
        float w = expf(lg);
        float4 hv = *(const float4*)(h + (size_t)d * 128 + 4 * l);
        acc.x += w * hv.x; acc.y += w * hv.y;
        acc.z += w * hv.z; acc.w += w * hv.w;
        wsum += w;
    }
    const float inv_dn = 1.f / wsum;
    float4 xv = *(const float4*)(x + (size_t)d * 128 + 4 * l);
    float4 bg = *(const float4*)(bgat + 4 * l);
    float v0 = xv.x + acc.x * inv_dn + bg.x;
    float v1 = xv.y + acc.y * inv_dn + bg.y;
    float v2 = xv.z + acc.z * inv_dn + bg.z;
    float v3 = xv.w + acc.w * inv_dn + bg.w;

    // LayerNorm over 128 channels = 32 lanes x 4
    float s = v0 + v1 + v2 + v3;
    #pragma unroll
    for (int off = 16; off; off >>= 1) s += __shfl_xor(s, off, 32);
    float mu = s * (1.f / 128.f);
    float d0 = v0 - mu, d1 = v1 - mu, d2 = v2 - mu, d3 = v3 - mu;
    float q = d0 * d0 + d1 * d1 + d2 * d2 + d3 * d3;
    #pragma unroll
    for (int off = 16; off; off >>= 1) q += __shfl_xor(q, off, 32);
    float inv = rsqrtf(q * (1.f / 128.f) + LN_EPS);

    float4 gv = ((const float4*)g1)[l];
    float4 bv = ((const float4*)b1)[l];
    float4 o;
    o.x = d0 * inv * gv.x + bv.x;
    o.y = d1 * inv * gv.y + bv.y;
    o.z = d2 * inv * gv.z + bv.z;
    o.w = d3 * inv * gv.w + bv.w;
    ((float4*)(h1 + (size_t)d * 128))[l] = o;
}

// ---------------------------------------------------------------------------
// Kernel 6: FF block, fused per 32-node tile:
//   t = relu(h1@W1 + b1) (LDS), y = t@W2 + b2, out = LN2(h1 + y).
// h1 and out may alias (tile fully read before written).
// ---------------------------------------------------------------------------
#define BN 32
__global__ __launch_bounds__(256) void k_ff(
    const float* __restrict__ h1g, const float* __restrict__ W1,
    const float* __restrict__ b1, const float* __restrict__ W2,
    const float* __restrict__ b2, const float* __restrict__ g2,
    const float* __restrict__ bln2, float* __restrict__ out, int nn)
{
    __shared__ float sh1[BN][128];
    __shared__ float st[BN][512];
    const int tid = threadIdx.x;
    const int base = blockIdx.x * BN;

    for (int i = tid; i < BN * 32; i += 256) {
        int row = i >> 5;
        float4 v = make_float4(0.f, 0.f, 0.f, 0.f);
        if (base + row < nn) v = ((const float4*)(h1g + (size_t)(base + row) * 128))[i & 31];
        ((float4*)sh1)[i] = v;
    }
    __syncthreads();

    // phase 2: hidden = relu(h1@W1 + b1). thread owns cols j0=tid, j1=tid+256.
    {
        const int j0 = tid, j1 = tid + 256;
        float acc0[BN], acc1[BN];
        float bb0 = b1[j0], bb1 = b1[j1];
        #pragma unroll
        for (int n = 0; n < BN; ++n) { acc0[n] = bb0; acc1[n] = bb1; }
        for (int k4 = 0; k4 < 32; ++k4) {
            float w0[4], w1[4];
            #pragma unroll
            for (int i = 0; i < 4; ++i) {
                w0[i] = W1[(size_t)(k4 * 4 + i) * 512 + j0];
                w1[i] = W1[(size_t)(k4 * 4 + i) * 512 + j1];
            }
            #pragma unroll
            for (int n = 0; n < BN; ++n) {
                float4 xv = *(const float4*)&sh1[n][k4 * 4];
                acc0[n] += xv.x * w0[0] + xv.y * w0[1] + xv.z * w0[2] + xv.w * w0[3];
                acc1[n] += xv.x * w1[0] + xv.y * w1[1] + xv.z * w1[2] + xv.w * w1[3];
            }
        }
        #pragma unroll
        for (int n = 0; n < BN; ++n) {
            st[n][j0] = fmaxf(acc0[n], 0.f);
            st[n][j1] = fmaxf(acc1[n], 0.f);
        }
    }
    __syncthreads();

    // phase 3: y = t@W2 + b2. thread: col jj=tid&127, nodes (tid>>7)*16..+15
    {
        const int jj = tid & 127, half = tid >> 7;
        float acc[16];
        float bb = b2[jj];
        #pragma unroll
        for (int n = 0; n < 16; ++n) acc[n] = bb;
        for (int k4 = 0; k4 < 128; ++k4) {
            float w[4];
            #pragma unroll
            for (int i = 0; i < 4; ++i) w[i] = W2[(size_t)(k4 * 4 + i) * 128 + jj];
            #pragma unroll
            for (int n = 0; n < 16; ++n) {
                float4 tv = *(const float4*)&st[half * 16 + n][k4 * 4];
                acc[n] += tv.x * w[0] + tv.y * w[1] + tv.z * w[2] + tv.w * w[3];
            }
        }
        __syncthreads();  // everyone done READING st before we overwrite it
        float* sv = &st[0][0];  // reuse as [32][128] v = h1 + y
        #pragma unroll
        for (int n = 0; n < 16; ++n)
            sv[(size_t)(half * 16 + n) * 128 + jj] = acc[n] + sh1[half * 16 + n][jj];
    }
    __syncthreads();

    // phase 4: LN2 per node; wave per node (4 waves x 8 nodes)
    {
        const int wv = tid >> 6, lane = tid & 63;
        const float* sv = &st[0][0];
        float2 gv = ((const float2*)g2)[lane];
        float2 bv = ((const float2*)bln2)[lane];
        for (int r = 0; r < 8; ++r) {
            int n = wv * 8 + r;
            if (base + n >= nn) break;
            float v0 = sv[(size_t)n * 128 + 2 * lane];
            float v1 = sv[(size_t)n * 128 + 2 * lane + 1];
            float s = v0 + v1;
            #pragma unroll
            for (int off = 32; off; off >>= 1) s += __shfl_xor(s, off, 64);
            float mu = s * (1.f / 128.f);
            float d0 = v0 - mu, d1 = v1 - mu;
            float q = d0 * d0 + d1 * d1;
            #pragma unroll
            for (int off = 32; off; off >>= 1) q += __shfl_xor(q, off, 64);
            float inv = rsqrtf(q * (1.f / 128.f) + LN_EPS);
            float2 o;
            o.x = d0 * inv * gv.x + bv.x;
            o.y = d1 * inv * gv.y + bv.y;
            ((float2*)(out + (size_t)(base + n) * 128))[lane] = o;
        }
    }
}

// ---------------------------------------------------------------------------
extern "C" void kernel_launch(void* const* d_in, const int* in_sizes, int n_in,
                              void* d_out, int out_size, void* d_ws, size_t ws_size,
                              hipStream_t stream) {
    const float* x    = (const float*)d_in[0];
    const int*   ei   = (const int*)d_in[1];
    const float* Wg   = (const float*)d_in[2];
    const float* atts = (const float*)d_in[3];
    const float* attd = (const float*)d_in[4];
    const float* bgat = (const float*)d_in[5];
    const float* W1   = (const float*)d_in[6];
    const float* b1   = (const float*)d_in[7];
    const float* W2   = (const float*)d_in[8];
    const float* b2   = (const float*)d_in[9];
    const float* g1   = (const float*)d_in[10];
    const float* bln1 = (const float*)d_in[11];
    const float* g2   = (const float*)d_in[12];
    const float* bln2 = (const float*)d_in[13];
    float* out = (float*)d_out;

    const int nn = in_sizes[0] / 128;
    const int E  = in_sizes[1] / 2;

    // workspace: h (nn*128 f) | a_s (nn*8) | a_d (nn*8) | ptr (nn i) | esrc (E i)
    float* ws  = (float*)d_ws;
    float* h   = ws;
    float* a_s = h + (size_t)nn * 128;
    float* a_d = a_s + (size_t)nn * 8;
    int*   ptr = (int*)(a_d + (size_t)nn * 8);
    int*   esrc = ptr + nn;

    hipMemsetAsync(ptr, 0, (size_t)nn * sizeof(int), stream);

    k_gat_proj<<<dim3((nn + 31) / 32), dim3(256), 0, stream>>>(x, Wg, atts, attd, h, a_s, a_d, nn);
    k_deg<<<dim3((E + 255) / 256), dim3(256), 0, stream>>>(ei, ptr, E);
    k_scan<<<dim3(1), dim3(1024), 0, stream>>>(ptr, nn);
    k_scatter<<<dim3((E + 255) / 256), dim3(256), 0, stream>>>(ei, ptr, esrc, E);
    k_gather<<<dim3((nn * 32 + 255) / 256), dim3(256), 0, stream>>>(
        esrc, ptr, h, a_s, a_d, x, bgat, g1, bln1, out, nn);
    k_ff<<<dim3((nn + BN - 1) / BN), dim3(256), 0, stream>>>(out, W1, b1, W2, b2, g2, bln2, out, nn);
}

// Round 3
// 673.666 us; speedup vs baseline: 3.5147x; 1.8004x over previous
//
#include <hip/hip_runtime.h>
#include <hip/hip_bf16.h>
#include <cstddef>
#include <cstdint>

#define NEG_SLOPE 0.2f
#define LN_EPS 1e-5f

typedef __attribute__((ext_vector_type(8))) short bf16x8;
typedef __attribute__((ext_vector_type(4))) float f32x4;

__device__ __forceinline__ unsigned short f2bf(float f) {
    __hip_bfloat16 h = __float2bfloat16(f);
    return *reinterpret_cast<unsigned short*>(&h);
}

// ---------------------------------------------------------------------------
// Kernel 1: h = x @ W_gat (N x 128 @ 128 x 128) + attention logits a_s, a_d.
// ---------------------------------------------------------------------------
__global__ __launch_bounds__(256) void k_gat_proj(
    const float* __restrict__ x, const float* __restrict__ Wg,
    const float* __restrict__ atts, const float* __restrict__ attd,
    float* __restrict__ h, float* __restrict__ a_s, float* __restrict__ a_d,
    int nn)
{
    __shared__ float sW[128 * 128];     // [k][j], 64 KB
    __shared__ float sx[32][128];       // 16 KB
    __shared__ float4 sas[32], sad[32];

    const int tid = threadIdx.x;
    const int base = blockIdx.x * 32;

    for (int i = tid; i < 4096; i += 256)
        ((float4*)sW)[i] = ((const float4*)Wg)[i];
    if (tid < 32) { sas[tid] = ((const float4*)atts)[tid]; sad[tid] = ((const float4*)attd)[tid]; }
    for (int i = tid; i < 1024; i += 256) {
        int row = i >> 5;
        float4 v = make_float4(0.f, 0.f, 0.f, 0.f);
        if (base + row < nn) v = ((const float4*)(x + (size_t)(base + row) * 128))[i & 31];
        ((float4*)sx)[i] = v;
    }
    __syncthreads();

    const int colg = tid & 31;
    const int rs   = tid >> 5;

    float4 acc[4];
    #pragma unroll
    for (int r = 0; r < 4; ++r) acc[r] = make_float4(0.f, 0.f, 0.f, 0.f);

    #pragma unroll 4
    for (int k = 0; k < 128; ++k) {
        float4 wv = ((const float4*)(sW + k * 128))[colg];
        #pragma unroll
        for (int r = 0; r < 4; ++r) {
            float xv = sx[rs + 8 * r][k];
            acc[r].x += xv * wv.x; acc[r].y += xv * wv.y;
            acc[r].z += xv * wv.z; acc[r].w += xv * wv.w;
        }
    }

    float4 as4 = sas[colg], ad4 = sad[colg];
    #pragma unroll
    for (int r = 0; r < 4; ++r) {
        int n = base + rs + 8 * r;
        float ps = acc[r].x * as4.x + acc[r].y * as4.y + acc[r].z * as4.z + acc[r].w * as4.w;
        float pd = acc[r].x * ad4.x + acc[r].y * ad4.y + acc[r].z * ad4.z + acc[r].w * ad4.w;
        ps += __shfl_xor(ps, 1, 4); ps += __shfl_xor(ps, 2, 4);
        pd += __shfl_xor(pd, 1, 4); pd += __shfl_xor(pd, 2, 4);
        if (n < nn) {
            ((float4*)(h + (size_t)n * 128))[colg] = acc[r];
            if ((colg & 3) == 0) {
                int head = colg >> 2;
                a_s[(size_t)n * 8 + head] = ps;
                a_d[(size_t)n * 8 + head] = pd;
            }
        }
    }
}

// ---------------------------------------------------------------------------
// CSR binning.
// ---------------------------------------------------------------------------
__global__ __launch_bounds__(256) void k_deg(
    const int* __restrict__ ei, int* __restrict__ deg, int E)
{
    int e = blockIdx.x * 256 + threadIdx.x;
    if (e < E) atomicAdd(&deg[ei[(size_t)E + e]], 1);
}

__global__ __launch_bounds__(1024) void k_scan(int* __restrict__ ptr, int nn)
{
    __shared__ int part[1024];
    const int tid = threadIdx.x;
    const int chunk = (nn + 1023) >> 10;
    const int lo = tid * chunk;
    const int hi = min(lo + chunk, nn);
    int s = 0;
    for (int i = lo; i < hi; ++i) s += ptr[i];
    part[tid] = s;
    __syncthreads();
    for (int d = 1; d < 1024; d <<= 1) {
        int add = (tid >= d) ? part[tid - d] : 0;
        __syncthreads();
        part[tid] += add;
        __syncthreads();
    }
    int off = (tid == 0) ? 0 : part[tid - 1];
    for (int i = lo; i < hi; ++i) { int v = ptr[i]; ptr[i] = off; off += v; }
}

__global__ __launch_bounds__(256) void k_scatter(
    const int* __restrict__ ei, int* __restrict__ ptr,
    int* __restrict__ esrc, int E)
{
    int e = blockIdx.x * 256 + threadIdx.x;
    if (e < E) {
        int pos = atomicAdd(&ptr[ei[(size_t)E + e]], 1);
        esrc[pos] = ei[e];
    }
}

// ---------------------------------------------------------------------------
// Gather + softmax + self-loop + residual + LN1 fused. Half-wave per dst.
// Writes h1 fp32 into d_out AND h1 bf16 into h1b (for the MFMA FF).
// ---------------------------------------------------------------------------
__global__ __launch_bounds__(256) void k_gather(
    const int* __restrict__ esrc, const int* __restrict__ ptr,
    const float* __restrict__ h, const float* __restrict__ a_s,
    const float* __restrict__ a_d, const float* __restrict__ x,
    const float* __restrict__ bgat, const float* __restrict__ g1,
    const float* __restrict__ b1, float* __restrict__ h1,
    unsigned short* __restrict__ h1b, int nn)
{
    int d = (blockIdx.x * 256 + threadIdx.x) >> 5;
    if (d >= nn) return;
    const int l = threadIdx.x & 31;
    const int head = l >> 2;

    const int start = (d == 0) ? 0 : ptr[d - 1];
    const int end = ptr[d];
    const float ad = a_d[(size_t)d * 8 + head];

    float4 acc = make_float4(0.f, 0.f, 0.f, 0.f);
    float wsum = 0.f;
    for (int e = start; e < end; ++e) {
        int s = esrc[e];
        float lg = a_s[(size_t)s * 8 + head] + ad;
        lg = (lg >= 0.f) ? lg : NEG_SLOPE * lg;
        float w = expf(lg);
        float4 hv = *(const float4*)(h + (size_t)s * 128 + 4 * l);
        acc.x += w * hv.x; acc.y += w * hv.y;
        acc.z += w * hv.z; acc.w += w * hv.w;
        wsum += w;
    }
    {   // self loop
        float lg = a_s[(size_t)d * 8 + head] + ad;
        lg = (lg >= 0.f) ? lg : NEG_SLOPE * lg;
        float w = expf(lg);
        float4 hv = *(const float4*)(h + (size_t)d * 128 + 4 * l);
        acc.x += w * hv.x; acc.y += w * hv.y;
        acc.z += w * hv.z; acc.w += w * hv.w;
        wsum += w;
    }
    const float inv_dn = 1.f / wsum;
    float4 xv = *(const float4*)(x + (size_t)d * 128 + 4 * l);
    float4 bg = *(const float4*)(bgat + 4 * l);
    float v0 = xv.x + acc.x * inv_dn + bg.x;
    float v1 = xv.y + acc.y * inv_dn + bg.y;
    float v2 = xv.z + acc.z * inv_dn + bg.z;
    float v3 = xv.w + acc.w * inv_dn + bg.w;

    float s = v0 + v1 + v2 + v3;
    #pragma unroll
    for (int off = 16; off; off >>= 1) s += __shfl_xor(s, off, 32);
    float mu = s * (1.f / 128.f);
    float d0 = v0 - mu, d1 = v1 - mu, d2 = v2 - mu, d3 = v3 - mu;
    float q = d0 * d0 + d1 * d1 + d2 * d2 + d3 * d3;
    #pragma unroll
    for (int off = 16; off; off >>= 1) q += __shfl_xor(q, off, 32);
    float inv = rsqrtf(q * (1.f / 128.f) + LN_EPS);

    float4 gv = ((const float4*)g1)[l];
    float4 bv = ((const float4*)b1)[l];
    float4 o;
    o.x = d0 * inv * gv.x + bv.x;
    o.y = d1 * inv * gv.y + bv.y;
    o.z = d2 * inv * gv.z + bv.z;
    o.w = d3 * inv * gv.w + bv.w;
    ((float4*)(h1 + (size_t)d * 128))[l] = o;
    ushort4 ob;
    ob.x = f2bf(o.x); ob.y = f2bf(o.y); ob.z = f2bf(o.z); ob.w = f2bf(o.w);
    ((ushort4*)(h1b + (size_t)d * 128))[l] = ob;
}

// ---------------------------------------------------------------------------
// Weight transpose + bf16 convert: W1t[n][k]=W1[k][n] (512x128),
// W2t[n][k]=W2[k][n] (128x512). B^T layout -> contiguous-k b-fragments.
// ---------------------------------------------------------------------------
__global__ __launch_bounds__(256) void k_cvt(
    const float* __restrict__ W1, const float* __restrict__ W2,
    unsigned short* __restrict__ W1t, unsigned short* __restrict__ W2t)
{
    int t = blockIdx.x * 256 + threadIdx.x;
    if (t < 512 * 128) {
        int n = t >> 7, k = t & 127;
        W1t[t] = f2bf(W1[(size_t)k * 512 + n]);
        int n2 = t >> 9, k2 = t & 511;
        W2t[t] = f2bf(W2[(size_t)k2 * 128 + n2]);
    }
}

// ---------------------------------------------------------------------------
// FF block via bf16 MFMA (fp32 accumulate), 32-node tile, 4 waves.
// GEMM1: wave w -> n in [w*128,(w+1)*128); 2 row-tiles x 8 col-tiles x 4 k.
// GEMM2: wave w -> n in [w*32,(w+1)*32);   2 row-tiles x 2 col-tiles x 16 k.
// t kept bf16 in LDS (padded rows: 2-way bank aliasing only, free).
// Residual reads h1 fp32 from global; LN2 staged through reused st space.
// A-frag: A[m=lane&15][k=quad*8+j]; B-frag from B^T: Bt[n=lane&15][k=quad*8+j];
// C/D: row=quad*4+r, col=lane&15 (m89/m91 verified layouts).
// ---------------------------------------------------------------------------
__global__ __launch_bounds__(256, 3) void k_ffm(
    const unsigned short* __restrict__ h1b, const float* __restrict__ h1f,
    const unsigned short* __restrict__ W1t, const float* __restrict__ b1,
    const unsigned short* __restrict__ W2t, const float* __restrict__ b2,
    const float* __restrict__ g2, const float* __restrict__ bln2,
    float* __restrict__ out, int nn)
{
    __shared__ __align__(16) unsigned short sh1[32][136];  // 8.5 KB
    __shared__ __align__(16) unsigned short st[32][520];   // 33.3 KB

    const int tid  = threadIdx.x;
    const int base = blockIdx.x * 32;
    const int lane = tid & 63;
    const int w    = tid >> 6;
    const int ln   = lane & 15;
    const int quad = lane >> 4;

    // stage h1 bf16 -> LDS (16B chunks)
    for (int i = tid; i < 512; i += 256) {
        int row = i >> 4, c = i & 15;
        bf16x8 v = {0, 0, 0, 0, 0, 0, 0, 0};
        if (base + row < nn)
            v = *(const bf16x8*)(h1b + (size_t)(base + row) * 128 + c * 8);
        *(bf16x8*)&sh1[row][c * 8] = v;
    }
    __syncthreads();

    // ---- GEMM1: t = relu(h1 @ W1 + b1) ----
    {
        bf16x8 a[2][4];
        #pragma unroll
        for (int mt = 0; mt < 2; ++mt)
            #pragma unroll
            for (int ks = 0; ks < 4; ++ks)
                a[mt][ks] = *(const bf16x8*)&sh1[mt * 16 + ln][ks * 32 + quad * 8];

        f32x4 acc[2][8];
        #pragma unroll
        for (int mt = 0; mt < 2; ++mt)
            #pragma unroll
            for (int nt = 0; nt < 8; ++nt)
                acc[mt][nt] = (f32x4){0.f, 0.f, 0.f, 0.f};

        #pragma unroll
        for (int nt = 0; nt < 8; ++nt) {
            const unsigned short* bp =
                W1t + (size_t)(w * 128 + nt * 16 + ln) * 128 + quad * 8;
            #pragma unroll
            for (int ks = 0; ks < 4; ++ks) {
                bf16x8 b = *(const bf16x8*)(bp + ks * 32);
                acc[0][nt] = __builtin_amdgcn_mfma_f32_16x16x32_bf16(a[0][ks], b, acc[0][nt], 0, 0, 0);
                acc[1][nt] = __builtin_amdgcn_mfma_f32_16x16x32_bf16(a[1][ks], b, acc[1][nt], 0, 0, 0);
            }
        }
        #pragma unroll
        for (int nt = 0; nt < 8; ++nt) {
            float bb = b1[w * 128 + nt * 16 + ln];
            #pragma unroll
            for (int mt = 0; mt < 2; ++mt)
                #pragma unroll
                for (int r = 0; r < 4; ++r) {
                    float v = fmaxf(acc[mt][nt][r] + bb, 0.f);
                    st[mt * 16 + quad * 4 + r][w * 128 + nt * 16 + ln] = f2bf(v);
                }
        }
    }
    __syncthreads();

    // ---- GEMM2: y = t @ W2 + b2; v = y + h1 ----
    float vout[2][2][4];
    {
        f32x4 acc[2][2];
        #pragma unroll
        for (int mt = 0; mt < 2; ++mt)
            #pragma unroll
            for (int nt = 0; nt < 2; ++nt)
                acc[mt][nt] = (f32x4){0.f, 0.f, 0.f, 0.f};

        for (int ks = 0; ks < 16; ++ks) {
            bf16x8 a0 = *(const bf16x8*)&st[ln][ks * 32 + quad * 8];
            bf16x8 a1 = *(const bf16x8*)&st[16 + ln][ks * 32 + quad * 8];
            const unsigned short* bp =
                W2t + (size_t)(w * 32 + ln) * 512 + ks * 32 + quad * 8;
            bf16x8 b0 = *(const bf16x8*)bp;
            bf16x8 b1v = *(const bf16x8*)(bp + 16 * 512);
            acc[0][0] = __builtin_amdgcn_mfma_f32_16x16x32_bf16(a0, b0,  acc[0][0], 0, 0, 0);
            acc[0][1] = __builtin_amdgcn_mfma_f32_16x16x32_bf16(a0, b1v, acc[0][1], 0, 0, 0);
            acc[1][0] = __builtin_amdgcn_mfma_f32_16x16x32_bf16(a1, b0,  acc[1][0], 0, 0, 0);
            acc[1][1] = __builtin_amdgcn_mfma_f32_16x16x32_bf16(a1, b1v, acc[1][1], 0, 0, 0);
        }
        #pragma unroll
        for (int nt = 0; nt < 2; ++nt) {
            int n = w * 32 + nt * 16 + ln;
            float bb = b2[n];
            #pragma unroll
            for (int mt = 0; mt < 2; ++mt)
                #pragma unroll
                for (int r = 0; r < 4; ++r) {
                    int m = mt * 16 + quad * 4 + r;
                    float hv = (base + m < nn) ? h1f[(size_t)(base + m) * 128 + n] : 0.f;
                    vout[mt][nt][r] = acc[mt][nt][r] + bb + hv;
                }
        }
    }
    __syncthreads();   // all st reads done before reuse

    float* sv = (float*)&st[0][0];  // reuse as [32][128] fp32
    #pragma unroll
    for (int nt = 0; nt < 2; ++nt)
        #pragma unroll
        for (int mt = 0; mt < 2; ++mt)
            #pragma unroll
            for (int r = 0; r < 4; ++r) {
                int m = mt * 16 + quad * 4 + r;
                int n = w * 32 + nt * 16 + ln;
                sv[m * 128 + n] = vout[mt][nt][r];
            }
    __syncthreads();

    // ---- LN2: wave per node, 8 nodes/wave ----
    {
        float2 gv = ((const float2*)g2)[lane];
        float2 bv = ((const float2*)bln2)[lane];
        for (int r = 0; r < 8; ++r) {
            int m = w * 8 + r;
            if (base + m >= nn) break;
            float v0 = sv[m * 128 + 2 * lane];
            float v1 = sv[m * 128 + 2 * lane + 1];
            float s = v0 + v1;
            #pragma unroll
            for (int off = 32; off; off >>= 1) s += __shfl_xor(s, off, 64);
            float mu = s * (1.f / 128.f);
            float d0 = v0 - mu, d1 = v1 - mu;
            float q = d0 * d0 + d1 * d1;
            #pragma unroll
            for (int off = 32; off; off >>= 1) q += __shfl_xor(q, off, 64);
            float inv = rsqrtf(q * (1.f / 128.f) + LN_EPS);
            float2 o;
            o.x = d0 * inv * gv.x + bv.x;
            o.y = d1 * inv * gv.y + bv.y;
            ((float2*)(out + (size_t)(base + m) * 128))[lane] = o;
        }
    }
}

// ---------------------------------------------------------------------------
extern "C" void kernel_launch(void* const* d_in, const int* in_sizes, int n_in,
                              void* d_out, int out_size, void* d_ws, size_t ws_size,
                              hipStream_t stream) {
    const float* x    = (const float*)d_in[0];
    const int*   ei   = (const int*)d_in[1];
    const float* Wg   = (const float*)d_in[2];
    const float* atts = (const float*)d_in[3];
    const float* attd = (const float*)d_in[4];
    const float* bgat = (const float*)d_in[5];
    const float* W1   = (const float*)d_in[6];
    const float* b1   = (const float*)d_in[7];
    const float* W2   = (const float*)d_in[8];
    const float* b2   = (const float*)d_in[9];
    const float* g1   = (const float*)d_in[10];
    const float* bln1 = (const float*)d_in[11];
    const float* g2   = (const float*)d_in[12];
    const float* bln2 = (const float*)d_in[13];
    float* out = (float*)d_out;

    const int nn = in_sizes[0] / 128;
    const int E  = in_sizes[1] / 2;

    // workspace: h | a_s | a_d | ptr | esrc | (align16) W1t | W2t | h1b
    float* ws  = (float*)d_ws;
    float* h   = ws;
    float* a_s = h + (size_t)nn * 128;
    float* a_d = a_s + (size_t)nn * 8;
    int*   ptr = (int*)(a_d + (size_t)nn * 8);
    int*   esrc = ptr + nn;
    uintptr_t p = (uintptr_t)(esrc + E);
    p = (p + 15) & ~(uintptr_t)15;
    unsigned short* W1t = (unsigned short*)p;
    unsigned short* W2t = W1t + 512 * 128;
    unsigned short* h1b = W2t + 128 * 512;

    hipMemsetAsync(ptr, 0, (size_t)nn * sizeof(int), stream);

    k_cvt<<<dim3(256), dim3(256), 0, stream>>>(W1, W2, W1t, W2t);
    k_gat_proj<<<dim3((nn + 31) / 32), dim3(256), 0, stream>>>(x, Wg, atts, attd, h, a_s, a_d, nn);
    k_deg<<<dim3((E + 255) / 256), dim3(256), 0, stream>>>(ei, ptr, E);
    k_scan<<<dim3(1), dim3(1024), 0, stream>>>(ptr, nn);
    k_scatter<<<dim3((E + 255) / 256), dim3(256), 0, stream>>>(ei, ptr, esrc, E);
    k_gather<<<dim3((nn * 32 + 255) / 256), dim3(256), 0, stream>>>(
        esrc, ptr, h, a_s, a_d, x, bgat, g1, bln1, out, h1b, nn);
    k_ffm<<<dim3((nn + 31) / 32), dim3(256), 0, stream>>>(
        h1b, out, W1t, b1, W2t, b2, g2, bln2, out, nn);
}

// Round 4
// 515.670 us; speedup vs baseline: 4.5916x; 1.3064x over previous
//
#include <hip/hip_runtime.h>
#include <hip/hip_bf16.h>
#include <cstddef>
#include <cstdint>

#define NEG_SLOPE 0.2f
#define LN_EPS 1e-5f

typedef __attribute__((ext_vector_type(8))) short bf16x8;
typedef __attribute__((ext_vector_type(4))) float f32x4;

__device__ __forceinline__ unsigned short f2bf(float f) {
    __hip_bfloat16 h = __float2bfloat16(f);
    return *reinterpret_cast<unsigned short*>(&h);
}

// ---------------------------------------------------------------------------
// Kernel 1: h = x @ W_gat (N x 128 @ 128 x 128) + attention logits a_s, a_d.
// ---------------------------------------------------------------------------
__global__ __launch_bounds__(256) void k_gat_proj(
    const float* __restrict__ x, const float* __restrict__ Wg,
    const float* __restrict__ atts, const float* __restrict__ attd,
    float* __restrict__ h, float* __restrict__ a_s, float* __restrict__ a_d,
    int nn)
{
    __shared__ float sW[128 * 128];     // [k][j], 64 KB
    __shared__ float sx[32][128];       // 16 KB
    __shared__ float4 sas[32], sad[32];

    const int tid = threadIdx.x;
    const int base = blockIdx.x * 32;

    for (int i = tid; i < 4096; i += 256)
        ((float4*)sW)[i] = ((const float4*)Wg)[i];
    if (tid < 32) { sas[tid] = ((const float4*)atts)[tid]; sad[tid] = ((const float4*)attd)[tid]; }
    for (int i = tid; i < 1024; i += 256) {
        int row = i >> 5;
        float4 v = make_float4(0.f, 0.f, 0.f, 0.f);
        if (base + row < nn) v = ((const float4*)(x + (size_t)(base + row) * 128))[i & 31];
        ((float4*)sx)[i] = v;
    }
    __syncthreads();

    const int colg = tid & 31;
    const int rs   = tid >> 5;

    float4 acc[4];
    #pragma unroll
    for (int r = 0; r < 4; ++r) acc[r] = make_float4(0.f, 0.f, 0.f, 0.f);

    #pragma unroll 4
    for (int k = 0; k < 128; ++k) {
        float4 wv = ((const float4*)(sW + k * 128))[colg];
        #pragma unroll
        for (int r = 0; r < 4; ++r) {
            float xv = sx[rs + 8 * r][k];
            acc[r].x += xv * wv.x; acc[r].y += xv * wv.y;
            acc[r].z += xv * wv.z; acc[r].w += xv * wv.w;
        }
    }

    float4 as4 = sas[colg], ad4 = sad[colg];
    #pragma unroll
    for (int r = 0; r < 4; ++r) {
        int n = base + rs + 8 * r;
        float ps = acc[r].x * as4.x + acc[r].y * as4.y + acc[r].z * as4.z + acc[r].w * as4.w;
        float pd = acc[r].x * ad4.x + acc[r].y * ad4.y + acc[r].z * ad4.z + acc[r].w * ad4.w;
        ps += __shfl_xor(ps, 1, 4); ps += __shfl_xor(ps, 2, 4);
        pd += __shfl_xor(pd, 1, 4); pd += __shfl_xor(pd, 2, 4);
        if (n < nn) {
            ((float4*)(h + (size_t)n * 128))[colg] = acc[r];
            if ((colg & 3) == 0) {
                int head = colg >> 2;
                a_s[(size_t)n * 8 + head] = ps;
                a_d[(size_t)n * 8 + head] = pd;
            }
        }
    }
}

// ---------------------------------------------------------------------------
// CSR binning: deg histogram -> two-level exclusive scan -> scatter.
// ---------------------------------------------------------------------------
__global__ __launch_bounds__(256) void k_deg(
    const int* __restrict__ ei, int* __restrict__ deg, int E)
{
    int e = blockIdx.x * 256 + threadIdx.x;
    if (e < E) atomicAdd(&deg[ei[(size_t)E + e]], 1);
}

// level 1: per-1024-chunk sums
__global__ __launch_bounds__(256) void k_scan_blk(
    const int* __restrict__ deg, int* __restrict__ bsum, int nn)
{
    __shared__ int ws[4];
    const int tid = threadIdx.x;
    const int base = blockIdx.x * 1024 + tid * 4;
    int4 v = make_int4(0, 0, 0, 0);
    if (base + 3 < nn) v = *(const int4*)(deg + base);
    else {
        if (base + 0 < nn) v.x = deg[base + 0];
        if (base + 1 < nn) v.y = deg[base + 1];
        if (base + 2 < nn) v.z = deg[base + 2];
    }
    int total = v.x + v.y + v.z + v.w;
    #pragma unroll
    for (int off = 32; off; off >>= 1) total += __shfl_xor(total, off, 64);
    if ((tid & 63) == 0) ws[tid >> 6] = total;
    __syncthreads();
    if (tid == 0) bsum[blockIdx.x] = ws[0] + ws[1] + ws[2] + ws[3];
}

// level 2: exclusive scan of block sums (nblk <= 1024)
__global__ __launch_bounds__(1024) void k_scan_top(int* __restrict__ bsum, int nblk)
{
    __shared__ int part[1024];
    const int tid = threadIdx.x;
    int v = (tid < nblk) ? bsum[tid] : 0;
    part[tid] = v;
    __syncthreads();
    for (int d = 1; d < 1024; d <<= 1) {
        int add = (tid >= d) ? part[tid - d] : 0;
        __syncthreads();
        part[tid] += add;
        __syncthreads();
    }
    if (tid < nblk) bsum[tid] = part[tid] - v;  // exclusive
}

// level 3: per-chunk exclusive scan + block offset -> ptr (start offsets)
__global__ __launch_bounds__(256) void k_scan_out(
    const int* __restrict__ deg, const int* __restrict__ bsum,
    int* __restrict__ ptr, int nn)
{
    __shared__ int ws[4];
    const int tid = threadIdx.x;
    const int lane = tid & 63;
    const int wid = tid >> 6;
    const int base = blockIdx.x * 1024 + tid * 4;
    int4 v = make_int4(0, 0, 0, 0);
    if (base + 3 < nn) v = *(const int4*)(deg + base);
    else {
        if (base + 0 < nn) v.x = deg[base + 0];
        if (base + 1 < nn) v.y = deg[base + 1];
        if (base + 2 < nn) v.z = deg[base + 2];
    }
    int t1 = v.x + v.y, t2 = t1 + v.z;
    int total = t2 + v.w;
    int inc = total;
    #pragma unroll
    for (int off = 1; off < 64; off <<= 1) {
        int y = __shfl_up(inc, off, 64);
        if (lane >= off) inc += y;
    }
    int wexcl = inc - total;
    if (lane == 63) ws[wid] = inc;
    __syncthreads();
    int woff = 0;
    #pragma unroll
    for (int i = 0; i < 4; ++i) if (i < wid) woff += ws[i];
    int e0 = bsum[blockIdx.x] + woff + wexcl;
    int4 o;
    o.x = e0; o.y = e0 + v.x; o.z = e0 + t1; o.w = e0 + t2;
    if (base + 3 < nn) *(int4*)(ptr + base) = o;
    else {
        if (base + 0 < nn) ptr[base + 0] = o.x;
        if (base + 1 < nn) ptr[base + 1] = o.y;
        if (base + 2 < nn) ptr[base + 2] = o.z;
    }
}

__global__ __launch_bounds__(256) void k_scatter(
    const int* __restrict__ ei, int* __restrict__ ptr,
    int* __restrict__ esrc, int E)
{
    int e = blockIdx.x * 256 + threadIdx.x;
    if (e < E) {
        int pos = atomicAdd(&ptr[ei[(size_t)E + e]], 1);
        esrc[pos] = ei[e];
    }
}

// ---------------------------------------------------------------------------
// Gather + softmax + self-loop + residual + LN1 fused. Half-wave per dst.
// Writes h1 fp32 into d_out AND h1 bf16 into h1b (for the MFMA FF).
// ---------------------------------------------------------------------------
__global__ __launch_bounds__(256) void k_gather(
    const int* __restrict__ esrc, const int* __restrict__ ptr,
    const float* __restrict__ h, const float* __restrict__ a_s,
    const float* __restrict__ a_d, const float* __restrict__ x,
    const float* __restrict__ bgat, const float* __restrict__ g1,
    const float* __restrict__ b1, float* __restrict__ h1,
    unsigned short* __restrict__ h1b, int nn)
{
    int d = (blockIdx.x * 256 + threadIdx.x) >> 5;
    if (d >= nn) return;
    const int l = threadIdx.x & 31;
    const int head = l >> 2;

    const int start = (d == 0) ? 0 : ptr[d - 1];
    const int end = ptr[d];
    const float ad = a_d[(size_t)d * 8 + head];

    float4 acc = make_float4(0.f, 0.f, 0.f, 0.f);
    float wsum = 0.f;
    for (int e = start; e < end; ++e) {
        int s = esrc[e];
        float lg = a_s[(size_t)s * 8 + head] + ad;
        lg = (lg >= 0.f) ? lg : NEG_SLOPE * lg;
        float w = expf(lg);
        float4 hv = *(const float4*)(h + (size_t)s * 128 + 4 * l);
        acc.x += w * hv.x; acc.y += w * hv.y;
        acc.z += w * hv.z; acc.w += w * hv.w;
        wsum += w;
    }
    {   // self loop
        float lg = a_s[(size_t)d * 8 + head] + ad;
        lg = (lg >= 0.f) ? lg : NEG_SLOPE * lg;
        float w = expf(lg);
        float4 hv = *(const float4*)(h + (size_t)d * 128 + 4 * l);
        acc.x += w * hv.x; acc.y += w * hv.y;
        acc.z += w * hv.z; acc.w += w * hv.w;
        wsum += w;
    }
    const float inv_dn = 1.f / wsum;
    float4 xv = *(const float4*)(x + (size_t)d * 128 + 4 * l);
    float4 bg = *(const float4*)(bgat + 4 * l);
    float v0 = xv.x + acc.x * inv_dn + bg.x;
    float v1 = xv.y + acc.y * inv_dn + bg.y;
    float v2 = xv.z + acc.z * inv_dn + bg.z;
    float v3 = xv.w + acc.w * inv_dn + bg.w;

    float s = v0 + v1 + v2 + v3;
    #pragma unroll
    for (int off = 16; off; off >>= 1) s += __shfl_xor(s, off, 32);
    float mu = s * (1.f / 128.f);
    float d0 = v0 - mu, d1 = v1 - mu, d2 = v2 - mu, d3 = v3 - mu;
    float q = d0 * d0 + d1 * d1 + d2 * d2 + d3 * d3;
    #pragma unroll
    for (int off = 16; off; off >>= 1) q += __shfl_xor(q, off, 32);
    float inv = rsqrtf(q * (1.f / 128.f) + LN_EPS);

    float4 gv = ((const float4*)g1)[l];
    float4 bv = ((const float4*)b1)[l];
    float4 o;
    o.x = d0 * inv * gv.x + bv.x;
    o.y = d1 * inv * gv.y + bv.y;
    o.z = d2 * inv * gv.z + bv.z;
    o.w = d3 * inv * gv.w + bv.w;
    ((float4*)(h1 + (size_t)d * 128))[l] = o;
    ushort4 ob;
    ob.x = f2bf(o.x); ob.y = f2bf(o.y); ob.z = f2bf(o.z); ob.w = f2bf(o.w);
    ((ushort4*)(h1b + (size_t)d * 128))[l] = ob;
}

// ---------------------------------------------------------------------------
// Weight transpose + bf16 convert (B^T layouts for MFMA b-fragments).
// ---------------------------------------------------------------------------
__global__ __launch_bounds__(256) void k_cvt(
    const float* __restrict__ W1, const float* __restrict__ W2,
    unsigned short* __restrict__ W1t, unsigned short* __restrict__ W2t)
{
    int t = blockIdx.x * 256 + threadIdx.x;
    if (t < 512 * 128) {
        int n = t >> 7, k = t & 127;
        W1t[t] = f2bf(W1[(size_t)k * 512 + n]);
        int n2 = t >> 9, k2 = t & 511;
        W2t[t] = f2bf(W2[(size_t)k2 * 128 + n2]);
    }
}

// ---------------------------------------------------------------------------
// FF block via bf16 MFMA (fp32 accumulate), 32-node tile, 4 waves.
// ---------------------------------------------------------------------------
__global__ __launch_bounds__(256, 3) void k_ffm(
    const unsigned short* __restrict__ h1b, const float* __restrict__ h1f,
    const unsigned short* __restrict__ W1t, const float* __restrict__ b1,
    const unsigned short* __restrict__ W2t, const float* __restrict__ b2,
    const float* __restrict__ g2, const float* __restrict__ bln2,
    float* __restrict__ out, int nn)
{
    __shared__ __align__(16) unsigned short sh1[32][136];  // 8.5 KB
    __shared__ __align__(16) unsigned short st[32][520];   // 33.3 KB

    const int tid  = threadIdx.x;
    const int base = blockIdx.x * 32;
    const int lane = tid & 63;
    const int w    = tid >> 6;
    const int ln   = lane & 15;
    const int quad = lane >> 4;

    for (int i = tid; i < 512; i += 256) {
        int row = i >> 4, c = i & 15;
        bf16x8 v = {0, 0, 0, 0, 0, 0, 0, 0};
        if (base + row < nn)
            v = *(const bf16x8*)(h1b + (size_t)(base + row) * 128 + c * 8);
        *(bf16x8*)&sh1[row][c * 8] = v;
    }
    __syncthreads();

    // ---- GEMM1: t = relu(h1 @ W1 + b1) ----
    {
        bf16x8 a[2][4];
        #pragma unroll
        for (int mt = 0; mt < 2; ++mt)
            #pragma unroll
            for (int ks = 0; ks < 4; ++ks)
                a[mt][ks] = *(const bf16x8*)&sh1[mt * 16 + ln][ks * 32 + quad * 8];

        f32x4 acc[2][8];
        #pragma unroll
        for (int mt = 0; mt < 2; ++mt)
            #pragma unroll
            for (int nt = 0; nt < 8; ++nt)
                acc[mt][nt] = (f32x4){0.f, 0.f, 0.f, 0.f};

        #pragma unroll
        for (int nt = 0; nt < 8; ++nt) {
            const unsigned short* bp =
                W1t + (size_t)(w * 128 + nt * 16 + ln) * 128 + quad * 8;
            #pragma unroll
            for (int ks = 0; ks < 4; ++ks) {
                bf16x8 b = *(const bf16x8*)(bp + ks * 32);
                acc[0][nt] = __builtin_amdgcn_mfma_f32_16x16x32_bf16(a[0][ks], b, acc[0][nt], 0, 0, 0);
                acc[1][nt] = __builtin_amdgcn_mfma_f32_16x16x32_bf16(a[1][ks], b, acc[1][nt], 0, 0, 0);
            }
        }
        #pragma unroll
        for (int nt = 0; nt < 8; ++nt) {
            float bb = b1[w * 128 + nt * 16 + ln];
            #pragma unroll
            for (int mt = 0; mt < 2; ++mt)
                #pragma unroll
                for (int r = 0; r < 4; ++r) {
                    float v = fmaxf(acc[mt][nt][r] + bb, 0.f);
                    st[mt * 16 + quad * 4 + r][w * 128 + nt * 16 + ln] = f2bf(v);
                }
        }
    }
    __syncthreads();

    // ---- GEMM2: y = t @ W2 + b2; v = y + h1 ----
    float vout[2][2][4];
    {
        f32x4 acc[2][2];
        #pragma unroll
        for (int mt = 0; mt < 2; ++mt)
            #pragma unroll
            for (int nt = 0; nt < 2; ++nt)
                acc[mt][nt] = (f32x4){0.f, 0.f, 0.f, 0.f};

        for (int ks = 0; ks < 16; ++ks) {
            bf16x8 a0 = *(const bf16x8*)&st[ln][ks * 32 + quad * 8];
            bf16x8 a1 = *(const bf16x8*)&st[16 + ln][ks * 32 + quad * 8];
            const unsigned short* bp =
                W2t + (size_t)(w * 32 + ln) * 512 + ks * 32 + quad * 8;
            bf16x8 b0 = *(const bf16x8*)bp;
            bf16x8 b1v = *(const bf16x8*)(bp + 16 * 512);
            acc[0][0] = __builtin_amdgcn_mfma_f32_16x16x32_bf16(a0, b0,  acc[0][0], 0, 0, 0);
            acc[0][1] = __builtin_amdgcn_mfma_f32_16x16x32_bf16(a0, b1v, acc[0][1], 0, 0, 0);
            acc[1][0] = __builtin_amdgcn_mfma_f32_16x16x32_bf16(a1, b0,  acc[1][0], 0, 0, 0);
            acc[1][1] = __builtin_amdgcn_mfma_f32_16x16x32_bf16(a1, b1v, acc[1][1], 0, 0, 0);
        }
        #pragma unroll
        for (int nt = 0; nt < 2; ++nt) {
            int n = w * 32 + nt * 16 + ln;
            float bb = b2[n];
            #pragma unroll
            for (int mt = 0; mt < 2; ++mt)
                #pragma unroll
                for (int r = 0; r < 4; ++r) {
                    int m = mt * 16 + quad * 4 + r;
                    float hv = (base + m < nn) ? h1f[(size_t)(base + m) * 128 + n] : 0.f;
                    vout[mt][nt][r] = acc[mt][nt][r] + bb + hv;
                }
        }
    }
    __syncthreads();

    float* sv = (float*)&st[0][0];  // reuse as [32][128] fp32
    #pragma unroll
    for (int nt = 0; nt < 2; ++nt)
        #pragma unroll
        for (int mt = 0; mt < 2; ++mt)
            #pragma unroll
            for (int r = 0; r < 4; ++r) {
                int m = mt * 16 + quad * 4 + r;
                int n = w * 32 + nt * 16 + ln;
                sv[m * 128 + n] = vout[mt][nt][r];
            }
    __syncthreads();

    // ---- LN2: wave per node, 8 nodes/wave ----
    {
        float2 gv = ((const float2*)g2)[lane];
        float2 bv = ((const float2*)bln2)[lane];
        for (int r = 0; r < 8; ++r) {
            int m = w * 8 + r;
            if (base + m >= nn) break;
            float v0 = sv[m * 128 + 2 * lane];
            float v1 = sv[m * 128 + 2 * lane + 1];
            float s = v0 + v1;
            #pragma unroll
            for (int off = 32; off; off >>= 1) s += __shfl_xor(s, off, 64);
            float mu = s * (1.f / 128.f);
            float d0 = v0 - mu, d1 = v1 - mu;
            float q = d0 * d0 + d1 * d1;
            #pragma unroll
            for (int off = 32; off; off >>= 1) q += __shfl_xor(q, off, 64);
            float inv = rsqrtf(q * (1.f / 128.f) + LN_EPS);
            float2 o;
            o.x = d0 * inv * gv.x + bv.x;
            o.y = d1 * inv * gv.y + bv.y;
            ((float2*)(out + (size_t)(base + m) * 128))[lane] = o;
        }
    }
}

// ---------------------------------------------------------------------------
extern "C" void kernel_launch(void* const* d_in, const int* in_sizes, int n_in,
                              void* d_out, int out_size, void* d_ws, size_t ws_size,
                              hipStream_t stream) {
    const float* x    = (const float*)d_in[0];
    const int*   ei   = (const int*)d_in[1];
    const float* Wg   = (const float*)d_in[2];
    const float* atts = (const float*)d_in[3];
    const float* attd = (const float*)d_in[4];
    const float* bgat = (const float*)d_in[5];
    const float* W1   = (const float*)d_in[6];
    const float* b1   = (const float*)d_in[7];
    const float* W2   = (const float*)d_in[8];
    const float* b2   = (const float*)d_in[9];
    const float* g1   = (const float*)d_in[10];
    const float* bln1 = (const float*)d_in[11];
    const float* g2   = (const float*)d_in[12];
    const float* bln2 = (const float*)d_in[13];
    float* out = (float*)d_out;

    const int nn = in_sizes[0] / 128;
    const int E  = in_sizes[1] / 2;
    const int nblk = (nn + 1023) / 1024;

    // workspace: h | a_s | a_d | deg | ptr | bsum | esrc | (align16) W1t | W2t | h1b
    float* ws  = (float*)d_ws;
    float* h   = ws;
    float* a_s = h + (size_t)nn * 128;
    float* a_d = a_s + (size_t)nn * 8;
    int*   deg = (int*)(a_d + (size_t)nn * 8);
    int*   ptr = deg + nn;
    int*   bsum = ptr + nn;
    int*   esrc = bsum + ((nblk + 255) & ~255);
    uintptr_t p = (uintptr_t)(esrc + E);
    p = (p + 15) & ~(uintptr_t)15;
    unsigned short* W1t = (unsigned short*)p;
    unsigned short* W2t = W1t + 512 * 128;
    unsigned short* h1b = W2t + 128 * 512;

    hipMemsetAsync(deg, 0, (size_t)nn * sizeof(int), stream);

    k_cvt<<<dim3(256), dim3(256), 0, stream>>>(W1, W2, W1t, W2t);
    k_gat_proj<<<dim3((nn + 31) / 32), dim3(256), 0, stream>>>(x, Wg, atts, attd, h, a_s, a_d, nn);
    k_deg<<<dim3((E + 255) / 256), dim3(256), 0, stream>>>(ei, deg, E);
    k_scan_blk<<<dim3(nblk), dim3(256), 0, stream>>>(deg, bsum, nn);
    k_scan_top<<<dim3(1), dim3(1024), 0, stream>>>(bsum, nblk);
    k_scan_out<<<dim3(nblk), dim3(256), 0, stream>>>(deg, bsum, ptr, nn);
    k_scatter<<<dim3((E + 255) / 256), dim3(256), 0, stream>>>(ei, ptr, esrc, E);
    k_gather<<<dim3((nn * 32 + 255) / 256), dim3(256), 0, stream>>>(
        esrc, ptr, h, a_s, a_d, x, bgat, g1, bln1, out, h1b, nn);
    k_ffm<<<dim3((nn + 31) / 32), dim3(256), 0, stream>>>(
        h1b, out, W1t, b1, W2t, b2, g2, bln2, out, nn);
}

// Round 5
// 438.423 us; speedup vs baseline: 5.4006x; 1.1762x over previous
//
#include <hip/hip_runtime.h>
#include <hip/hip_bf16.h>
#include <cstddef>
#include <cstdint>

#define NEG_SLOPE 0.2f
#define LN_EPS 1e-5f

typedef __attribute__((ext_vector_type(8))) short bf16x8;
typedef __attribute__((ext_vector_type(4))) float f32x4;

__device__ __forceinline__ unsigned short f2bf(float f) {
    __hip_bfloat16 h = __float2bfloat16(f);
    return *reinterpret_cast<unsigned short*>(&h);
}

// ---------------------------------------------------------------------------
// GAT projection via bf16 MFMA: h = x @ W_gat (N x 128 @ 128 x 128), fp32 out,
// plus per-head logits a_s/a_d. 64-node tile, 4 waves; wave = 16 rows.
// Col-tile nt == head nt (C=16), so logits reduce out of the accumulator
// with a width-16 shuffle. LDS rows padded +8 bf16 -> 2-way aliasing (free).
// ---------------------------------------------------------------------------
__global__ __launch_bounds__(256, 3) void k_gat_projm(
    const float* __restrict__ x, const unsigned short* __restrict__ Wgt,
    const float* __restrict__ atts, const float* __restrict__ attd,
    float* __restrict__ h, float* __restrict__ a_s, float* __restrict__ a_d,
    int nn)
{
    __shared__ __align__(16) unsigned short sx[64][136];   // 17.4 KB
    __shared__ __align__(16) unsigned short sw[128][136];  // 34.8 KB

    const int tid  = threadIdx.x;
    const int base = blockIdx.x * 64;
    const int lane = tid & 63;
    const int w    = tid >> 6;
    const int ln   = lane & 15;
    const int quad = lane >> 4;

    // stage Wgt (bf16, B^T layout [n][k]) -> LDS
    for (int i = tid; i < 2048; i += 256) {
        int row = i >> 4, c = i & 15;
        *(bf16x8*)&sw[row][c * 8] = *(const bf16x8*)(Wgt + row * 128 + c * 8);
    }
    // stage x (fp32 -> bf16) -> LDS
    for (int i = tid; i < 2048; i += 256) {
        int row = i >> 5, c = i & 31;
        float4 v = make_float4(0.f, 0.f, 0.f, 0.f);
        if (base + row < nn) v = ((const float4*)(x + (size_t)(base + row) * 128))[c];
        ushort4 o;
        o.x = f2bf(v.x); o.y = f2bf(v.y); o.z = f2bf(v.z); o.w = f2bf(v.w);
        *(ushort4*)&sx[row][c * 4] = o;
    }
    __syncthreads();

    bf16x8 a[4];
    #pragma unroll
    for (int ks = 0; ks < 4; ++ks)
        a[ks] = *(const bf16x8*)&sx[w * 16 + ln][ks * 32 + quad * 8];

    f32x4 acc[8];
    #pragma unroll
    for (int nt = 0; nt < 8; ++nt) acc[nt] = (f32x4){0.f, 0.f, 0.f, 0.f};

    #pragma unroll
    for (int nt = 0; nt < 8; ++nt)
        #pragma unroll
        for (int ks = 0; ks < 4; ++ks) {
            bf16x8 b = *(const bf16x8*)&sw[nt * 16 + ln][ks * 32 + quad * 8];
            acc[nt] = __builtin_amdgcn_mfma_f32_16x16x32_bf16(a[ks], b, acc[nt], 0, 0, 0);
        }

    // epilogue: write h (fp32) + reduce per-head logits
    #pragma unroll
    for (int nt = 0; nt < 8; ++nt) {
        float av = atts[nt * 16 + ln];
        float dv = attd[nt * 16 + ln];
        #pragma unroll
        for (int r = 0; r < 4; ++r) {
            int node = base + w * 16 + quad * 4 + r;
            float val = acc[nt][r];
            float ps = val * av, pd = val * dv;
            #pragma unroll
            for (int off = 1; off < 16; off <<= 1) {
                ps += __shfl_xor(ps, off, 16);
                pd += __shfl_xor(pd, off, 16);
            }
            if (node < nn) {
                h[(size_t)node * 128 + nt * 16 + ln] = val;
                if (ln == 0) {
                    a_s[(size_t)node * 8 + nt] = ps;
                    a_d[(size_t)node * 8 + nt] = pd;
                }
            }
        }
    }
}

// ---------------------------------------------------------------------------
// CSR binning: deg histogram -> two-level exclusive scan -> scatter.
// ---------------------------------------------------------------------------
__global__ __launch_bounds__(256) void k_deg(
    const int* __restrict__ ei, int* __restrict__ deg, int E)
{
    int e = blockIdx.x * 256 + threadIdx.x;
    if (e < E) atomicAdd(&deg[ei[(size_t)E + e]], 1);
}

__global__ __launch_bounds__(256) void k_scan_blk(
    const int* __restrict__ deg, int* __restrict__ bsum, int nn)
{
    __shared__ int ws[4];
    const int tid = threadIdx.x;
    const int base = blockIdx.x * 1024 + tid * 4;
    int4 v = make_int4(0, 0, 0, 0);
    if (base + 3 < nn) v = *(const int4*)(deg + base);
    else {
        if (base + 0 < nn) v.x = deg[base + 0];
        if (base + 1 < nn) v.y = deg[base + 1];
        if (base + 2 < nn) v.z = deg[base + 2];
    }
    int total = v.x + v.y + v.z + v.w;
    #pragma unroll
    for (int off = 32; off; off >>= 1) total += __shfl_xor(total, off, 64);
    if ((tid & 63) == 0) ws[tid >> 6] = total;
    __syncthreads();
    if (tid == 0) bsum[blockIdx.x] = ws[0] + ws[1] + ws[2] + ws[3];
}

__global__ __launch_bounds__(1024) void k_scan_top(int* __restrict__ bsum, int nblk)
{
    __shared__ int part[1024];
    const int tid = threadIdx.x;
    int v = (tid < nblk) ? bsum[tid] : 0;
    part[tid] = v;
    __syncthreads();
    for (int d = 1; d < 1024; d <<= 1) {
        int add = (tid >= d) ? part[tid - d] : 0;
        __syncthreads();
        part[tid] += add;
        __syncthreads();
    }
    if (tid < nblk) bsum[tid] = part[tid] - v;  // exclusive
}

__global__ __launch_bounds__(256) void k_scan_out(
    const int* __restrict__ deg, const int* __restrict__ bsum,
    int* __restrict__ ptr, int nn)
{
    __shared__ int ws[4];
    const int tid = threadIdx.x;
    const int lane = tid & 63;
    const int wid = tid >> 6;
    const int base = blockIdx.x * 1024 + tid * 4;
    int4 v = make_int4(0, 0, 0, 0);
    if (base + 3 < nn) v = *(const int4*)(deg + base);
    else {
        if (base + 0 < nn) v.x = deg[base + 0];
        if (base + 1 < nn) v.y = deg[base + 1];
        if (base + 2 < nn) v.z = deg[base + 2];
    }
    int t1 = v.x + v.y, t2 = t1 + v.z;
    int total = t2 + v.w;
    int inc = total;
    #pragma unroll
    for (int off = 1; off < 64; off <<= 1) {
        int y = __shfl_up(inc, off, 64);
        if (lane >= off) inc += y;
    }
    int wexcl = inc - total;
    if (lane == 63) ws[wid] = inc;
    __syncthreads();
    int woff = 0;
    #pragma unroll
    for (int i = 0; i < 4; ++i) if (i < wid) woff += ws[i];
    int e0 = bsum[blockIdx.x] + woff + wexcl;
    int4 o;
    o.x = e0; o.y = e0 + v.x; o.z = e0 + t1; o.w = e0 + t2;
    if (base + 3 < nn) *(int4*)(ptr + base) = o;
    else {
        if (base + 0 < nn) ptr[base + 0] = o.x;
        if (base + 1 < nn) ptr[base + 1] = o.y;
        if (base + 2 < nn) ptr[base + 2] = o.z;
    }
}

__global__ __launch_bounds__(256) void k_scatter(
    const int* __restrict__ ei, int* __restrict__ ptr,
    int* __restrict__ esrc, int E)
{
    int e = blockIdx.x * 256 + threadIdx.x;
    if (e < E) {
        int pos = atomicAdd(&ptr[ei[(size_t)E + e]], 1);
        esrc[pos] = ei[e];
    }
}

// ---------------------------------------------------------------------------
// Gather + softmax + self-loop + residual + LN1 fused. Half-wave per dst.
// Writes h1 fp32 into d_out AND h1 bf16 into h1b (for the MFMA FF).
// ---------------------------------------------------------------------------
__global__ __launch_bounds__(256) void k_gather(
    const int* __restrict__ esrc, const int* __restrict__ ptr,
    const float* __restrict__ h, const float* __restrict__ a_s,
    const float* __restrict__ a_d, const float* __restrict__ x,
    const float* __restrict__ bgat, const float* __restrict__ g1,
    const float* __restrict__ b1, float* __restrict__ h1,
    unsigned short* __restrict__ h1b, int nn)
{
    int d = (blockIdx.x * 256 + threadIdx.x) >> 5;
    if (d >= nn) return;
    const int l = threadIdx.x & 31;
    const int head = l >> 2;

    const int start = (d == 0) ? 0 : ptr[d - 1];
    const int end = ptr[d];
    const float ad = a_d[(size_t)d * 8 + head];

    float4 acc = make_float4(0.f, 0.f, 0.f, 0.f);
    float wsum = 0.f;
    for (int e = start; e < end; ++e) {
        int s = esrc[e];
        float lg = a_s[(size_t)s * 8 + head] + ad;
        lg = (lg >= 0.f) ? lg : NEG_SLOPE * lg;
        float w = expf(lg);
        float4 hv = *(const float4*)(h + (size_t)s * 128 + 4 * l);
        acc.x += w * hv.x; acc.y += w * hv.y;
        acc.z += w * hv.z; acc.w += w * hv.w;
        wsum += w;
    }
    {   // self loop
        float lg = a_s[(size_t)d * 8 + head] + ad;
        lg = (lg >= 0.f) ? lg : NEG_SLOPE * lg;
        float w = expf(lg);
        float4 hv = *(const float4*)(h + (size_t)d * 128 + 4 * l);
        acc.x += w * hv.x; acc.y += w * hv.y;
        acc.z += w * hv.z; acc.w += w * hv.w;
        wsum += w;
    }
    const float inv_dn = 1.f / wsum;
    float4 xv = *(const float4*)(x + (size_t)d * 128 + 4 * l);
    float4 bg = *(const float4*)(bgat + 4 * l);
    float v0 = xv.x + acc.x * inv_dn + bg.x;
    float v1 = xv.y + acc.y * inv_dn + bg.y;
    float v2 = xv.z + acc.z * inv_dn + bg.z;
    float v3 = xv.w + acc.w * inv_dn + bg.w;

    float s = v0 + v1 + v2 + v3;
    #pragma unroll
    for (int off = 16; off; off >>= 1) s += __shfl_xor(s, off, 32);
    float mu = s * (1.f / 128.f);
    float d0 = v0 - mu, d1 = v1 - mu, d2 = v2 - mu, d3 = v3 - mu;
    float q = d0 * d0 + d1 * d1 + d2 * d2 + d3 * d3;
    #pragma unroll
    for (int off = 16; off; off >>= 1) q += __shfl_xor(q, off, 32);
    float inv = rsqrtf(q * (1.f / 128.f) + LN_EPS);

    float4 gv = ((const float4*)g1)[l];
    float4 bv = ((const float4*)b1)[l];
    float4 o;
    o.x = d0 * inv * gv.x + bv.x;
    o.y = d1 * inv * gv.y + bv.y;
    o.z = d2 * inv * gv.z + bv.z;
    o.w = d3 * inv * gv.w + bv.w;
    ((float4*)(h1 + (size_t)d * 128))[l] = o;
    ushort4 ob;
    ob.x = f2bf(o.x); ob.y = f2bf(o.y); ob.z = f2bf(o.z); ob.w = f2bf(o.w);
    ((ushort4*)(h1b + (size_t)d * 128))[l] = ob;
}

// ---------------------------------------------------------------------------
// Weight transpose + bf16 convert (B^T layouts for MFMA b-fragments).
// Also converts W_gat -> Wgt (128x128 transposed bf16).
// ---------------------------------------------------------------------------
__global__ __launch_bounds__(256) void k_cvt(
    const float* __restrict__ W1, const float* __restrict__ W2,
    const float* __restrict__ Wg,
    unsigned short* __restrict__ W1t, unsigned short* __restrict__ W2t,
    unsigned short* __restrict__ Wgt)
{
    int t = blockIdx.x * 256 + threadIdx.x;
    if (t < 512 * 128) {
        int n = t >> 7, k = t & 127;
        W1t[t] = f2bf(W1[(size_t)k * 512 + n]);
        int n2 = t >> 9, k2 = t & 511;
        W2t[t] = f2bf(W2[(size_t)k2 * 128 + n2]);
        if (t < 128 * 128) {
            int n3 = t >> 7, k3 = t & 127;
            Wgt[t] = f2bf(Wg[(size_t)k3 * 128 + n3]);
        }
    }
}

// ---------------------------------------------------------------------------
// FF block via bf16 MFMA (fp32 accumulate), 32-node tile, 4 waves.
// ---------------------------------------------------------------------------
__global__ __launch_bounds__(256, 3) void k_ffm(
    const unsigned short* __restrict__ h1b, const float* __restrict__ h1f,
    const unsigned short* __restrict__ W1t, const float* __restrict__ b1,
    const unsigned short* __restrict__ W2t, const float* __restrict__ b2,
    const float* __restrict__ g2, const float* __restrict__ bln2,
    float* __restrict__ out, int nn)
{
    __shared__ __align__(16) unsigned short sh1[32][136];  // 8.5 KB
    __shared__ __align__(16) unsigned short st[32][520];   // 33.3 KB

    const int tid  = threadIdx.x;
    const int base = blockIdx.x * 32;
    const int lane = tid & 63;
    const int w    = tid >> 6;
    const int ln   = lane & 15;
    const int quad = lane >> 4;

    for (int i = tid; i < 512; i += 256) {
        int row = i >> 4, c = i & 15;
        bf16x8 v = {0, 0, 0, 0, 0, 0, 0, 0};
        if (base + row < nn)
            v = *(const bf16x8*)(h1b + (size_t)(base + row) * 128 + c * 8);
        *(bf16x8*)&sh1[row][c * 8] = v;
    }
    __syncthreads();

    // ---- GEMM1: t = relu(h1 @ W1 + b1) ----
    {
        bf16x8 a[2][4];
        #pragma unroll
        for (int mt = 0; mt < 2; ++mt)
            #pragma unroll
            for (int ks = 0; ks < 4; ++ks)
                a[mt][ks] = *(const bf16x8*)&sh1[mt * 16 + ln][ks * 32 + quad * 8];

        f32x4 acc[2][8];
        #pragma unroll
        for (int mt = 0; mt < 2; ++mt)
            #pragma unroll
            for (int nt = 0; nt < 8; ++nt)
                acc[mt][nt] = (f32x4){0.f, 0.f, 0.f, 0.f};

        #pragma unroll
        for (int nt = 0; nt < 8; ++nt) {
            const unsigned short* bp =
                W1t + (size_t)(w * 128 + nt * 16 + ln) * 128 + quad * 8;
            #pragma unroll
            for (int ks = 0; ks < 4; ++ks) {
                bf16x8 b = *(const bf16x8*)(bp + ks * 32);
                acc[0][nt] = __builtin_amdgcn_mfma_f32_16x16x32_bf16(a[0][ks], b, acc[0][nt], 0, 0, 0);
                acc[1][nt] = __builtin_amdgcn_mfma_f32_16x16x32_bf16(a[1][ks], b, acc[1][nt], 0, 0, 0);
            }
        }
        #pragma unroll
        for (int nt = 0; nt < 8; ++nt) {
            float bb = b1[w * 128 + nt * 16 + ln];
            #pragma unroll
            for (int mt = 0; mt < 2; ++mt)
                #pragma unroll
                for (int r = 0; r < 4; ++r) {
                    float v = fmaxf(acc[mt][nt][r] + bb, 0.f);
                    st[mt * 16 + quad * 4 + r][w * 128 + nt * 16 + ln] = f2bf(v);
                }
        }
    }
    __syncthreads();

    // ---- GEMM2: y = t @ W2 + b2; v = y + h1 ----
    float vout[2][2][4];
    {
        f32x4 acc[2][2];
        #pragma unroll
        for (int mt = 0; mt < 2; ++mt)
            #pragma unroll
            for (int nt = 0; nt < 2; ++nt)
                acc[mt][nt] = (f32x4){0.f, 0.f, 0.f, 0.f};

        for (int ks = 0; ks < 16; ++ks) {
            bf16x8 a0 = *(const bf16x8*)&st[ln][ks * 32 + quad * 8];
            bf16x8 a1 = *(const bf16x8*)&st[16 + ln][ks * 32 + quad * 8];
            const unsigned short* bp =
                W2t + (size_t)(w * 32 + ln) * 512 + ks * 32 + quad * 8;
            bf16x8 b0 = *(const bf16x8*)bp;
            bf16x8 b1v = *(const bf16x8*)(bp + 16 * 512);
            acc[0][0] = __builtin_amdgcn_mfma_f32_16x16x32_bf16(a0, b0,  acc[0][0], 0, 0, 0);
            acc[0][1] = __builtin_amdgcn_mfma_f32_16x16x32_bf16(a0, b1v, acc[0][1], 0, 0, 0);
            acc[1][0] = __builtin_amdgcn_mfma_f32_16x16x32_bf16(a1, b0,  acc[1][0], 0, 0, 0);
            acc[1][1] = __builtin_amdgcn_mfma_f32_16x16x32_bf16(a1, b1v, acc[1][1], 0, 0, 0);
        }
        #pragma unroll
        for (int nt = 0; nt < 2; ++nt) {
            int n = w * 32 + nt * 16 + ln;
            float bb = b2[n];
            #pragma unroll
            for (int mt = 0; mt < 2; ++mt)
                #pragma unroll
                for (int r = 0; r < 4; ++r) {
                    int m = mt * 16 + quad * 4 + r;
                    float hv = (base + m < nn) ? h1f[(size_t)(base + m) * 128 + n] : 0.f;
                    vout[mt][nt][r] = acc[mt][nt][r] + bb + hv;
                }
        }
    }
    __syncthreads();

    float* sv = (float*)&st[0][0];  // reuse as [32][128] fp32
    #pragma unroll
    for (int nt = 0; nt < 2; ++nt)
        #pragma unroll
        for (int mt = 0; mt < 2; ++mt)
            #pragma unroll
            for (int r = 0; r < 4; ++r) {
                int m = mt * 16 + quad * 4 + r;
                int n = w * 32 + nt * 16 + ln;
                sv[m * 128 + n] = vout[mt][nt][r];
            }
    __syncthreads();

    // ---- LN2: wave per node, 8 nodes/wave ----
    {
        float2 gv = ((const float2*)g2)[lane];
        float2 bv = ((const float2*)bln2)[lane];
        for (int r = 0; r < 8; ++r) {
            int m = w * 8 + r;
            if (base + m >= nn) break;
            float v0 = sv[m * 128 + 2 * lane];
            float v1 = sv[m * 128 + 2 * lane + 1];
            float s = v0 + v1;
            #pragma unroll
            for (int off = 32; off; off >>= 1) s += __shfl_xor(s, off, 64);
            float mu = s * (1.f / 128.f);
            float d0 = v0 - mu, d1 = v1 - mu;
            float q = d0 * d0 + d1 * d1;
            #pragma unroll
            for (int off = 32; off; off >>= 1) q += __shfl_xor(q, off, 64);
            float inv = rsqrtf(q * (1.f / 128.f) + LN_EPS);
            float2 o;
            o.x = d0 * inv * gv.x + bv.x;
            o.y = d1 * inv * gv.y + bv.y;
            ((float2*)(out + (size_t)(base + m) * 128))[lane] = o;
        }
    }
}

// ---------------------------------------------------------------------------
extern "C" void kernel_launch(void* const* d_in, const int* in_sizes, int n_in,
                              void* d_out, int out_size, void* d_ws, size_t ws_size,
                              hipStream_t stream) {
    const float* x    = (const float*)d_in[0];
    const int*   ei   = (const int*)d_in[1];
    const float* Wg   = (const float*)d_in[2];
    const float* atts = (const float*)d_in[3];
    const float* attd = (const float*)d_in[4];
    const float* bgat = (const float*)d_in[5];
    const float* W1   = (const float*)d_in[6];
    const float* b1   = (const float*)d_in[7];
    const float* W2   = (const float*)d_in[8];
    const float* b2   = (const float*)d_in[9];
    const float* g1   = (const float*)d_in[10];
    const float* bln1 = (const float*)d_in[11];
    const float* g2   = (const float*)d_in[12];
    const float* bln2 = (const float*)d_in[13];
    float* out = (float*)d_out;

    const int nn = in_sizes[0] / 128;
    const int E  = in_sizes[1] / 2;
    const int nblk = (nn + 1023) / 1024;

    // workspace: h | a_s | a_d | deg | ptr | bsum | esrc | (align16) W1t | W2t | Wgt | h1b
    float* ws  = (float*)d_ws;
    float* h   = ws;
    float* a_s = h + (size_t)nn * 128;
    float* a_d = a_s + (size_t)nn * 8;
    int*   deg = (int*)(a_d + (size_t)nn * 8);
    int*   ptr = deg + nn;
    int*   bsum = ptr + nn;
    int*   esrc = bsum + ((nblk + 255) & ~255);
    uintptr_t p = (uintptr_t)(esrc + E);
    p = (p + 15) & ~(uintptr_t)15;
    unsigned short* W1t = (unsigned short*)p;
    unsigned short* W2t = W1t + 512 * 128;
    unsigned short* Wgt = W2t + 128 * 512;
    unsigned short* h1b = Wgt + 128 * 128;

    hipMemsetAsync(deg, 0, (size_t)nn * sizeof(int), stream);

    k_cvt<<<dim3(256), dim3(256), 0, stream>>>(W1, W2, Wg, W1t, W2t, Wgt);
    k_gat_projm<<<dim3((nn + 63) / 64), dim3(256), 0, stream>>>(
        x, Wgt, atts, attd, h, a_s, a_d, nn);
    k_deg<<<dim3((E + 255) / 256), dim3(256), 0, stream>>>(ei, deg, E);
    k_scan_blk<<<dim3(nblk), dim3(256), 0, stream>>>(deg, bsum, nn);
    k_scan_top<<<dim3(1), dim3(1024), 0, stream>>>(bsum, nblk);
    k_scan_out<<<dim3(nblk), dim3(256), 0, stream>>>(deg, bsum, ptr, nn);
    k_scatter<<<dim3((E + 255) / 256), dim3(256), 0, stream>>>(ei, ptr, esrc, E);
    k_gather<<<dim3((nn * 32 + 255) / 256), dim3(256), 0, stream>>>(
        esrc, ptr, h, a_s, a_d, x, bgat, g1, bln1, out, h1b, nn);
    k_ffm<<<dim3((nn + 31) / 32), dim3(256), 0, stream>>>(
        h1b, out, W1t, b1, W2t, b2, g2, bln2, out, nn);
}

// Round 6
// 421.880 us; speedup vs baseline: 5.6124x; 1.0392x over previous
//
#include <hip/hip_runtime.h>
#include <hip/hip_bf16.h>
#include <cstddef>
#include <cstdint>

#define NEG_SLOPE 0.2f
#define LN_EPS 1e-5f

typedef __attribute__((ext_vector_type(8))) short bf16x8;
typedef __attribute__((ext_vector_type(4))) float f32x4;

__device__ __forceinline__ unsigned short f2bf(float f) {
    __hip_bfloat16 h = __float2bfloat16(f);
    return *reinterpret_cast<unsigned short*>(&h);
}
__device__ __forceinline__ float bf2f(unsigned short u) {
    return __uint_as_float(((unsigned)u) << 16);
}

// ---------------------------------------------------------------------------
// GAT projection via bf16 MFMA: h = x @ W_gat, stored bf16 (hb), plus per-head
// logits a_s/a_d (fp32, reduced from the fp32 accumulator before rounding).
// ---------------------------------------------------------------------------
__global__ __launch_bounds__(256, 3) void k_gat_projm(
    const float* __restrict__ x, const unsigned short* __restrict__ Wgt,
    const float* __restrict__ atts, const float* __restrict__ attd,
    unsigned short* __restrict__ hb, float* __restrict__ a_s,
    float* __restrict__ a_d, int nn)
{
    __shared__ __align__(16) unsigned short sx[64][136];   // 17.4 KB
    __shared__ __align__(16) unsigned short sw[128][136];  // 34.8 KB

    const int tid  = threadIdx.x;
    const int base = blockIdx.x * 64;
    const int lane = tid & 63;
    const int w    = tid >> 6;
    const int ln   = lane & 15;
    const int quad = lane >> 4;

    for (int i = tid; i < 2048; i += 256) {
        int row = i >> 4, c = i & 15;
        *(bf16x8*)&sw[row][c * 8] = *(const bf16x8*)(Wgt + row * 128 + c * 8);
    }
    for (int i = tid; i < 2048; i += 256) {
        int row = i >> 5, c = i & 31;
        float4 v = make_float4(0.f, 0.f, 0.f, 0.f);
        if (base + row < nn) v = ((const float4*)(x + (size_t)(base + row) * 128))[c];
        ushort4 o;
        o.x = f2bf(v.x); o.y = f2bf(v.y); o.z = f2bf(v.z); o.w = f2bf(v.w);
        *(ushort4*)&sx[row][c * 4] = o;
    }
    __syncthreads();

    bf16x8 a[4];
    #pragma unroll
    for (int ks = 0; ks < 4; ++ks)
        a[ks] = *(const bf16x8*)&sx[w * 16 + ln][ks * 32 + quad * 8];

    f32x4 acc[8];
    #pragma unroll
    for (int nt = 0; nt < 8; ++nt) acc[nt] = (f32x4){0.f, 0.f, 0.f, 0.f};

    #pragma unroll
    for (int nt = 0; nt < 8; ++nt)
        #pragma unroll
        for (int ks = 0; ks < 4; ++ks) {
            bf16x8 b = *(const bf16x8*)&sw[nt * 16 + ln][ks * 32 + quad * 8];
            acc[nt] = __builtin_amdgcn_mfma_f32_16x16x32_bf16(a[ks], b, acc[nt], 0, 0, 0);
        }

    #pragma unroll
    for (int nt = 0; nt < 8; ++nt) {
        float av = atts[nt * 16 + ln];
        float dv = attd[nt * 16 + ln];
        #pragma unroll
        for (int r = 0; r < 4; ++r) {
            int node = base + w * 16 + quad * 4 + r;
            float val = acc[nt][r];
            float ps = val * av, pd = val * dv;
            #pragma unroll
            for (int off = 1; off < 16; off <<= 1) {
                ps += __shfl_xor(ps, off, 16);
                pd += __shfl_xor(pd, off, 16);
            }
            if (node < nn) {
                hb[(size_t)node * 128 + nt * 16 + ln] = f2bf(val);
                if (ln == 0) {
                    a_s[(size_t)node * 8 + nt] = ps;
                    a_d[(size_t)node * 8 + nt] = pd;
                }
            }
        }
    }
}

// ---------------------------------------------------------------------------
// CSR binning: deg histogram -> two-level exclusive scan -> scatter.
// ---------------------------------------------------------------------------
__global__ __launch_bounds__(256) void k_deg(
    const int* __restrict__ ei, int* __restrict__ deg, int E)
{
    int e = blockIdx.x * 256 + threadIdx.x;
    if (e < E) atomicAdd(&deg[ei[(size_t)E + e]], 1);
}

__global__ __launch_bounds__(256) void k_scan_blk(
    const int* __restrict__ deg, int* __restrict__ bsum, int nn)
{
    __shared__ int ws[4];
    const int tid = threadIdx.x;
    const int base = blockIdx.x * 1024 + tid * 4;
    int4 v = make_int4(0, 0, 0, 0);
    if (base + 3 < nn) v = *(const int4*)(deg + base);
    else {
        if (base + 0 < nn) v.x = deg[base + 0];
        if (base + 1 < nn) v.y = deg[base + 1];
        if (base + 2 < nn) v.z = deg[base + 2];
    }
    int total = v.x + v.y + v.z + v.w;
    #pragma unroll
    for (int off = 32; off; off >>= 1) total += __shfl_xor(total, off, 64);
    if ((tid & 63) == 0) ws[tid >> 6] = total;
    __syncthreads();
    if (tid == 0) bsum[blockIdx.x] = ws[0] + ws[1] + ws[2] + ws[3];
}

__global__ __launch_bounds__(1024) void k_scan_top(int* __restrict__ bsum, int nblk)
{
    __shared__ int part[1024];
    const int tid = threadIdx.x;
    int v = (tid < nblk) ? bsum[tid] : 0;
    part[tid] = v;
    __syncthreads();
    for (int d = 1; d < 1024; d <<= 1) {
        int add = (tid >= d) ? part[tid - d] : 0;
        __syncthreads();
        part[tid] += add;
        __syncthreads();
    }
    if (tid < nblk) bsum[tid] = part[tid] - v;  // exclusive
}

__global__ __launch_bounds__(256) void k_scan_out(
    const int* __restrict__ deg, const int* __restrict__ bsum,
    int* __restrict__ ptr, int nn)
{
    __shared__ int ws[4];
    const int tid = threadIdx.x;
    const int lane = tid & 63;
    const int wid = tid >> 6;
    const int base = blockIdx.x * 1024 + tid * 4;
    int4 v = make_int4(0, 0, 0, 0);
    if (base + 3 < nn) v = *(const int4*)(deg + base);
    else {
        if (base + 0 < nn) v.x = deg[base + 0];
        if (base + 1 < nn) v.y = deg[base + 1];
        if (base + 2 < nn) v.z = deg[base + 2];
    }
    int t1 = v.x + v.y, t2 = t1 + v.z;
    int total = t2 + v.w;
    int inc = total;
    #pragma unroll
    for (int off = 1; off < 64; off <<= 1) {
        int y = __shfl_up(inc, off, 64);
        if (lane >= off) inc += y;
    }
    int wexcl = inc - total;
    if (lane == 63) ws[wid] = inc;
    __syncthreads();
    int woff = 0;
    #pragma unroll
    for (int i = 0; i < 4; ++i) if (i < wid) woff += ws[i];
    int e0 = bsum[blockIdx.x] + woff + wexcl;
    int4 o;
    o.x = e0; o.y = e0 + v.x; o.z = e0 + t1; o.w = e0 + t2;
    if (base + 3 < nn) *(int4*)(ptr + base) = o;
    else {
        if (base + 0 < nn) ptr[base + 0] = o.x;
        if (base + 1 < nn) ptr[base + 1] = o.y;
        if (base + 2 < nn) ptr[base + 2] = o.z;
    }
}

__global__ __launch_bounds__(256) void k_scatter(
    const int* __restrict__ ei, int* __restrict__ ptr,
    int* __restrict__ esrc, int E)
{
    int e = blockIdx.x * 256 + threadIdx.x;
    if (e < E) {
        int pos = atomicAdd(&ptr[ei[(size_t)E + e]], 1);
        esrc[pos] = ei[e];
    }
}

// ---------------------------------------------------------------------------
// Gather + softmax + self-loop + residual + LN1 fused. Half-wave per dst.
// Reads h in bf16 (hb); writes h1 ONLY in bf16 (h1b).
// ---------------------------------------------------------------------------
__global__ __launch_bounds__(256) void k_gather(
    const int* __restrict__ esrc, const int* __restrict__ ptr,
    const unsigned short* __restrict__ hb, const float* __restrict__ a_s,
    const float* __restrict__ a_d, const float* __restrict__ x,
    const float* __restrict__ bgat, const float* __restrict__ g1,
    const float* __restrict__ b1, unsigned short* __restrict__ h1b, int nn)
{
    int d = (blockIdx.x * 256 + threadIdx.x) >> 5;
    if (d >= nn) return;
    const int l = threadIdx.x & 31;
    const int head = l >> 2;

    const int start = (d == 0) ? 0 : ptr[d - 1];
    const int end = ptr[d];
    const float ad = a_d[(size_t)d * 8 + head];

    float4 acc = make_float4(0.f, 0.f, 0.f, 0.f);
    float wsum = 0.f;
    for (int e = start; e < end; ++e) {
        int s = esrc[e];
        float lg = a_s[(size_t)s * 8 + head] + ad;
        lg = (lg >= 0.f) ? lg : NEG_SLOPE * lg;
        float w = expf(lg);
        ushort4 hv = *(const ushort4*)(hb + (size_t)s * 128 + 4 * l);
        acc.x += w * bf2f(hv.x); acc.y += w * bf2f(hv.y);
        acc.z += w * bf2f(hv.z); acc.w += w * bf2f(hv.w);
        wsum += w;
    }
    {   // self loop
        float lg = a_s[(size_t)d * 8 + head] + ad;
        lg = (lg >= 0.f) ? lg : NEG_SLOPE * lg;
        float w = expf(lg);
        ushort4 hv = *(const ushort4*)(hb + (size_t)d * 128 + 4 * l);
        acc.x += w * bf2f(hv.x); acc.y += w * bf2f(hv.y);
        acc.z += w * bf2f(hv.z); acc.w += w * bf2f(hv.w);
        wsum += w;
    }
    const float inv_dn = 1.f / wsum;
    float4 xv = *(const float4*)(x + (size_t)d * 128 + 4 * l);
    float4 bg = *(const float4*)(bgat + 4 * l);
    float v0 = xv.x + acc.x * inv_dn + bg.x;
    float v1 = xv.y + acc.y * inv_dn + bg.y;
    float v2 = xv.z + acc.z * inv_dn + bg.z;
    float v3 = xv.w + acc.w * inv_dn + bg.w;

    float s = v0 + v1 + v2 + v3;
    #pragma unroll
    for (int off = 16; off; off >>= 1) s += __shfl_xor(s, off, 32);
    float mu = s * (1.f / 128.f);
    float d0 = v0 - mu, d1 = v1 - mu, d2 = v2 - mu, d3 = v3 - mu;
    float q = d0 * d0 + d1 * d1 + d2 * d2 + d3 * d3;
    #pragma unroll
    for (int off = 16; off; off >>= 1) q += __shfl_xor(q, off, 32);
    float inv = rsqrtf(q * (1.f / 128.f) + LN_EPS);

    float4 gv = ((const float4*)g1)[l];
    float4 bv = ((const float4*)b1)[l];
    ushort4 ob;
    ob.x = f2bf(d0 * inv * gv.x + bv.x);
    ob.y = f2bf(d1 * inv * gv.y + bv.y);
    ob.z = f2bf(d2 * inv * gv.z + bv.z);
    ob.w = f2bf(d3 * inv * gv.w + bv.w);
    ((ushort4*)(h1b + (size_t)d * 128))[l] = ob;
}

// ---------------------------------------------------------------------------
// Weight transpose + bf16 convert (B^T layouts for MFMA b-fragments).
// ---------------------------------------------------------------------------
__global__ __launch_bounds__(256) void k_cvt(
    const float* __restrict__ W1, const float* __restrict__ W2,
    const float* __restrict__ Wg,
    unsigned short* __restrict__ W1t, unsigned short* __restrict__ W2t,
    unsigned short* __restrict__ Wgt)
{
    int t = blockIdx.x * 256 + threadIdx.x;
    if (t < 512 * 128) {
        int n = t >> 7, k = t & 127;
        W1t[t] = f2bf(W1[(size_t)k * 512 + n]);
        int n2 = t >> 9, k2 = t & 511;
        W2t[t] = f2bf(W2[(size_t)k2 * 128 + n2]);
        if (t < 128 * 128) {
            int n3 = t >> 7, k3 = t & 127;
            Wgt[t] = f2bf(Wg[(size_t)k3 * 128 + n3]);
        }
    }
}

// ---------------------------------------------------------------------------
// FF GEMM1 (k-half p): t_half = relu(h1b @ W1[:, p*256 : p*256+256] + b1_half)
// Weight slice LDS-resident (70 KB, 2 blocks/CU). 512 thr = 8 waves; wave =
// 32 rows (2 m-tiles) x 256 cols. A-frags direct from global h1b (4/wave,
// reused across all n). B-frags via ds_read_b128.
// ---------------------------------------------------------------------------
__global__ __launch_bounds__(512, 4) void k_ff1(
    const unsigned short* __restrict__ h1b,
    const unsigned short* __restrict__ W1t,   // [512n][128k]
    const float* __restrict__ b1,
    unsigned short* __restrict__ th,          // [nn][256]
    int p, int nn)
{
    __shared__ __align__(16) unsigned short sw[256][136];  // 69.6 KB

    const int tid  = threadIdx.x;
    const int base = blockIdx.x * 256;
    const int lane = tid & 63;
    const int w    = tid >> 6;        // 0..7
    const int ln   = lane & 15;
    const int quad = lane >> 4;

    for (int i = tid; i < 4096; i += 512) {
        int row = i >> 4, c = i & 15;
        *(bf16x8*)&sw[row][c * 8] =
            *(const bf16x8*)(W1t + (size_t)(p * 256 + row) * 128 + c * 8);
    }
    __syncthreads();

    const bf16x8 zf = {0, 0, 0, 0, 0, 0, 0, 0};
    bf16x8 a[2][4];
    #pragma unroll
    for (int mt = 0; mt < 2; ++mt) {
        int node = base + (w * 2 + mt) * 16 + ln;
        #pragma unroll
        for (int ks = 0; ks < 4; ++ks)
            a[mt][ks] = (node < nn)
                ? *(const bf16x8*)(h1b + (size_t)node * 128 + ks * 32 + quad * 8)
                : zf;
    }

    for (int nc = 0; nc < 2; ++nc) {
        f32x4 acc[2][8];
        #pragma unroll
        for (int mt = 0; mt < 2; ++mt)
            #pragma unroll
            for (int nt = 0; nt < 8; ++nt)
                acc[mt][nt] = (f32x4){0.f, 0.f, 0.f, 0.f};

        #pragma unroll
        for (int nt = 0; nt < 8; ++nt)
            #pragma unroll
            for (int ks = 0; ks < 4; ++ks) {
                bf16x8 b = *(const bf16x8*)&sw[nc * 128 + nt * 16 + ln][ks * 32 + quad * 8];
                acc[0][nt] = __builtin_amdgcn_mfma_f32_16x16x32_bf16(a[0][ks], b, acc[0][nt], 0, 0, 0);
                acc[1][nt] = __builtin_amdgcn_mfma_f32_16x16x32_bf16(a[1][ks], b, acc[1][nt], 0, 0, 0);
            }

        #pragma unroll
        for (int nt = 0; nt < 8; ++nt) {
            int col = nc * 128 + nt * 16 + ln;
            float bb = b1[p * 256 + col];
            #pragma unroll
            for (int mt = 0; mt < 2; ++mt)
                #pragma unroll
                for (int r = 0; r < 4; ++r) {
                    int node = base + (w * 2 + mt) * 16 + quad * 4 + r;
                    if (node < nn)
                        th[(size_t)node * 256 + col] =
                            f2bf(fmaxf(acc[mt][nt][r] + bb, 0.f));
                }
        }
    }
}

// ---------------------------------------------------------------------------
// FF GEMM2 (k-half p): y_p = t_half @ W2[p*256:+256, :].
// p=0: out = y_0 (partial, fp32). p=1: out = LN2(y_0 + y_1 + b2 + h1), LN2
// computed fully in-register (wave owns all 128 cols of its rows; width-16
// shuffle reduce within each quad group).
// ---------------------------------------------------------------------------
__global__ __launch_bounds__(512, 4) void k_ff2(
    const unsigned short* __restrict__ th,    // [nn][256]
    const unsigned short* __restrict__ W2t,   // [128n][512k]
    const float* __restrict__ b2,
    const unsigned short* __restrict__ h1b,
    const float* __restrict__ g2, const float* __restrict__ bln2,
    float* __restrict__ out, int p, int nn)
{
    __shared__ __align__(16) unsigned short sw[128][264];  // 67.6 KB

    const int tid  = threadIdx.x;
    const int base = blockIdx.x * 256;
    const int lane = tid & 63;
    const int w    = tid >> 6;
    const int ln   = lane & 15;
    const int quad = lane >> 4;

    for (int i = tid; i < 4096; i += 512) {
        int row = i >> 5, c = i & 31;
        *(bf16x8*)&sw[row][c * 8] =
            *(const bf16x8*)(W2t + (size_t)row * 512 + p * 256 + c * 8);
    }
    __syncthreads();

    const bf16x8 zf = {0, 0, 0, 0, 0, 0, 0, 0};
    const int node0 = base + (w * 2 + 0) * 16 + ln;
    const int node1 = base + (w * 2 + 1) * 16 + ln;

    f32x4 acc[2][8];
    #pragma unroll
    for (int mt = 0; mt < 2; ++mt)
        #pragma unroll
        for (int nt = 0; nt < 8; ++nt)
            acc[mt][nt] = (f32x4){0.f, 0.f, 0.f, 0.f};

    for (int ks = 0; ks < 8; ++ks) {
        bf16x8 a0 = (node0 < nn)
            ? *(const bf16x8*)(th + (size_t)node0 * 256 + ks * 32 + quad * 8) : zf;
        bf16x8 a1 = (node1 < nn)
            ? *(const bf16x8*)(th + (size_t)node1 * 256 + ks * 32 + quad * 8) : zf;
        #pragma unroll
        for (int nt = 0; nt < 8; ++nt) {
            bf16x8 b = *(const bf16x8*)&sw[nt * 16 + ln][ks * 32 + quad * 8];
            acc[0][nt] = __builtin_amdgcn_mfma_f32_16x16x32_bf16(a0, b, acc[0][nt], 0, 0, 0);
            acc[1][nt] = __builtin_amdgcn_mfma_f32_16x16x32_bf16(a1, b, acc[1][nt], 0, 0, 0);
        }
    }

    if (p == 0) {
        #pragma unroll
        for (int mt = 0; mt < 2; ++mt)
            #pragma unroll
            for (int r = 0; r < 4; ++r) {
                int node = base + (w * 2 + mt) * 16 + quad * 4 + r;
                if (node < nn)
                    #pragma unroll
                    for (int nt = 0; nt < 8; ++nt)
                        out[(size_t)node * 128 + nt * 16 + ln] = acc[mt][nt][r];
            }
    } else {
        float gv[8], bv[8], bb[8];
        #pragma unroll
        for (int nt = 0; nt < 8; ++nt) {
            int col = nt * 16 + ln;
            gv[nt] = g2[col]; bv[nt] = bln2[col]; bb[nt] = b2[col];
        }
        #pragma unroll
        for (int mt = 0; mt < 2; ++mt) {
            #pragma unroll
            for (int r = 0; r < 4; ++r) {
                int node = base + (w * 2 + mt) * 16 + quad * 4 + r;
                bool ok = node < nn;
                float v[8];
                #pragma unroll
                for (int nt = 0; nt < 8; ++nt) {
                    int col = nt * 16 + ln;
                    float part = ok ? out[(size_t)node * 128 + col] : 0.f;
                    float res  = ok ? bf2f(h1b[(size_t)node * 128 + col]) : 0.f;
                    v[nt] = acc[mt][nt][r] + part + bb[nt] + res;
                }
                float s = 0.f;
                #pragma unroll
                for (int nt = 0; nt < 8; ++nt) s += v[nt];
                #pragma unroll
                for (int off = 1; off < 16; off <<= 1) s += __shfl_xor(s, off, 16);
                float mu = s * (1.f / 128.f);
                float q = 0.f;
                #pragma unroll
                for (int nt = 0; nt < 8; ++nt) { float dd = v[nt] - mu; q += dd * dd; }
                #pragma unroll
                for (int off = 1; off < 16; off <<= 1) q += __shfl_xor(q, off, 16);
                float inv = rsqrtf(q * (1.f / 128.f) + LN_EPS);
                if (ok)
                    #pragma unroll
                    for (int nt = 0; nt < 8; ++nt) {
                        int col = nt * 16 + ln;
                        out[(size_t)node * 128 + col] =
                            (v[nt] - mu) * inv * gv[nt] + bv[nt];
                    }
            }
        }
    }
}

// ---------------------------------------------------------------------------
extern "C" void kernel_launch(void* const* d_in, const int* in_sizes, int n_in,
                              void* d_out, int out_size, void* d_ws, size_t ws_size,
                              hipStream_t stream) {
    const float* x    = (const float*)d_in[0];
    const int*   ei   = (const int*)d_in[1];
    const float* Wg   = (const float*)d_in[2];
    const float* atts = (const float*)d_in[3];
    const float* attd = (const float*)d_in[4];
    const float* bgat = (const float*)d_in[5];
    const float* W1   = (const float*)d_in[6];
    const float* b1   = (const float*)d_in[7];
    const float* W2   = (const float*)d_in[8];
    const float* b2   = (const float*)d_in[9];
    const float* g1   = (const float*)d_in[10];
    const float* bln1 = (const float*)d_in[11];
    const float* g2   = (const float*)d_in[12];
    const float* bln2 = (const float*)d_in[13];
    float* out = (float*)d_out;

    const int nn = in_sizes[0] / 128;
    const int E  = in_sizes[1] / 2;
    const int nblk = (nn + 1023) / 1024;

    // workspace: W1t | W2t | Wgt | h1b | region{ phase1: hb|a_s|a_d|deg|ptr|bsum|esrc
    //                                            phase2: th (nn*256 bf16) }  ~77 MB
    uintptr_t pa = ((uintptr_t)d_ws + 15) & ~(uintptr_t)15;
    unsigned short* W1t = (unsigned short*)pa;
    unsigned short* W2t = W1t + 512 * 128;
    unsigned short* Wgt = W2t + 128 * 512;
    unsigned short* h1b = Wgt + 128 * 128;
    unsigned short* region = h1b + (size_t)nn * 128;
    // phase-1 view
    unsigned short* hb = region;
    float* a_s = (float*)(hb + (size_t)nn * 128);
    float* a_d = a_s + (size_t)nn * 8;
    int*   deg = (int*)(a_d + (size_t)nn * 8);
    int*   ptr = deg + nn;
    int*   bsum = ptr + nn;
    int*   esrc = bsum + 1024;
    // phase-2 view (aliases phase-1)
    unsigned short* th = region;

    hipMemsetAsync(deg, 0, (size_t)nn * sizeof(int), stream);

    k_cvt<<<dim3(256), dim3(256), 0, stream>>>(W1, W2, Wg, W1t, W2t, Wgt);
    k_gat_projm<<<dim3((nn + 63) / 64), dim3(256), 0, stream>>>(
        x, Wgt, atts, attd, hb, a_s, a_d, nn);
    k_deg<<<dim3((E + 255) / 256), dim3(256), 0, stream>>>(ei, deg, E);
    k_scan_blk<<<dim3(nblk), dim3(256), 0, stream>>>(deg, bsum, nn);
    k_scan_top<<<dim3(1), dim3(1024), 0, stream>>>(bsum, nblk);
    k_scan_out<<<dim3(nblk), dim3(256), 0, stream>>>(deg, bsum, ptr, nn);
    k_scatter<<<dim3((E + 255) / 256), dim3(256), 0, stream>>>(ei, ptr, esrc, E);
    k_gather<<<dim3((nn * 32 + 255) / 256), dim3(256), 0, stream>>>(
        esrc, ptr, hb, a_s, a_d, x, bgat, g1, bln1, h1b, nn);

    const int gff = (nn + 255) / 256;
    k_ff1<<<dim3(gff), dim3(512), 0, stream>>>(h1b, W1t, b1, th, 0, nn);
    k_ff2<<<dim3(gff), dim3(512), 0, stream>>>(th, W2t, b2, h1b, g2, bln2, out, 0, nn);
    k_ff1<<<dim3(gff), dim3(512), 0, stream>>>(h1b, W1t, b1, th, 1, nn);
    k_ff2<<<dim3(gff), dim3(512), 0, stream>>>(th, W2t, b2, h1b, g2, bln2, out, 1, nn);
}

// Round 7
// 415.625 us; speedup vs baseline: 5.6969x; 1.0150x over previous
//
#include <hip/hip_runtime.h>
#include <hip/hip_bf16.h>
#include <cstddef>
#include <cstdint>

#define NEG_SLOPE 0.2f
#define LN_EPS 1e-5f

typedef __attribute__((ext_vector_type(8))) short bf16x8;
typedef __attribute__((ext_vector_type(4))) float f32x4;

__device__ __forceinline__ unsigned short f2bf(float f) {
    __hip_bfloat16 h = __float2bfloat16(f);
    return *reinterpret_cast<unsigned short*>(&h);
}
__device__ __forceinline__ float bf2f(unsigned short u) {
    return __uint_as_float(((unsigned)u) << 16);
}
__device__ __forceinline__ float lrelu_exp(float e) {
    e = (e >= 0.f) ? e : NEG_SLOPE * e;
    return expf(e);
}

// ---------------------------------------------------------------------------
// GAT projection via bf16 MFMA: h = x @ W_gat, stored bf16 (hb), plus per-head
// logits a_s/a_d (fp32, reduced from the fp32 accumulator before rounding).
// ---------------------------------------------------------------------------
__global__ __launch_bounds__(256, 3) void k_gat_projm(
    const float* __restrict__ x, const unsigned short* __restrict__ Wgt,
    const float* __restrict__ atts, const float* __restrict__ attd,
    unsigned short* __restrict__ hb, float* __restrict__ a_s,
    float* __restrict__ a_d, int nn)
{
    __shared__ __align__(16) unsigned short sx[64][136];   // 17.4 KB
    __shared__ __align__(16) unsigned short sw[128][136];  // 34.8 KB

    const int tid  = threadIdx.x;
    const int base = blockIdx.x * 64;
    const int lane = tid & 63;
    const int w    = tid >> 6;
    const int ln   = lane & 15;
    const int quad = lane >> 4;

    for (int i = tid; i < 2048; i += 256) {
        int row = i >> 4, c = i & 15;
        *(bf16x8*)&sw[row][c * 8] = *(const bf16x8*)(Wgt + row * 128 + c * 8);
    }
    for (int i = tid; i < 2048; i += 256) {
        int row = i >> 5, c = i & 31;
        float4 v = make_float4(0.f, 0.f, 0.f, 0.f);
        if (base + row < nn) v = ((const float4*)(x + (size_t)(base + row) * 128))[c];
        ushort4 o;
        o.x = f2bf(v.x); o.y = f2bf(v.y); o.z = f2bf(v.z); o.w = f2bf(v.w);
        *(ushort4*)&sx[row][c * 4] = o;
    }
    __syncthreads();

    bf16x8 a[4];
    #pragma unroll
    for (int ks = 0; ks < 4; ++ks)
        a[ks] = *(const bf16x8*)&sx[w * 16 + ln][ks * 32 + quad * 8];

    f32x4 acc[8];
    #pragma unroll
    for (int nt = 0; nt < 8; ++nt) acc[nt] = (f32x4){0.f, 0.f, 0.f, 0.f};

    #pragma unroll
    for (int nt = 0; nt < 8; ++nt)
        #pragma unroll
        for (int ks = 0; ks < 4; ++ks) {
            bf16x8 b = *(const bf16x8*)&sw[nt * 16 + ln][ks * 32 + quad * 8];
            acc[nt] = __builtin_amdgcn_mfma_f32_16x16x32_bf16(a[ks], b, acc[nt], 0, 0, 0);
        }

    #pragma unroll
    for (int nt = 0; nt < 8; ++nt) {
        float av = atts[nt * 16 + ln];
        float dv = attd[nt * 16 + ln];
        #pragma unroll
        for (int r = 0; r < 4; ++r) {
            int node = base + w * 16 + quad * 4 + r;
            float val = acc[nt][r];
            float ps = val * av, pd = val * dv;
            #pragma unroll
            for (int off = 1; off < 16; off <<= 1) {
                ps += __shfl_xor(ps, off, 16);
                pd += __shfl_xor(pd, off, 16);
            }
            if (node < nn) {
                hb[(size_t)node * 128 + nt * 16 + ln] = f2bf(val);
                if (ln == 0) {
                    a_s[(size_t)node * 8 + nt] = ps;
                    a_d[(size_t)node * 8 + nt] = pd;
                }
            }
        }
    }
}

// ---------------------------------------------------------------------------
// CSR binning: deg histogram -> two-level exclusive scan -> scatter.
// ---------------------------------------------------------------------------
__global__ __launch_bounds__(256) void k_deg(
    const int* __restrict__ ei, int* __restrict__ deg, int E)
{
    int e = blockIdx.x * 256 + threadIdx.x;
    if (e < E) atomicAdd(&deg[ei[(size_t)E + e]], 1);
}

__global__ __launch_bounds__(256) void k_scan_blk(
    const int* __restrict__ deg, int* __restrict__ bsum, int nn)
{
    __shared__ int ws[4];
    const int tid = threadIdx.x;
    const int base = blockIdx.x * 1024 + tid * 4;
    int4 v = make_int4(0, 0, 0, 0);
    if (base + 3 < nn) v = *(const int4*)(deg + base);
    else {
        if (base + 0 < nn) v.x = deg[base + 0];
        if (base + 1 < nn) v.y = deg[base + 1];
        if (base + 2 < nn) v.z = deg[base + 2];
    }
    int total = v.x + v.y + v.z + v.w;
    #pragma unroll
    for (int off = 32; off; off >>= 1) total += __shfl_xor(total, off, 64);
    if ((tid & 63) == 0) ws[tid >> 6] = total;
    __syncthreads();
    if (tid == 0) bsum[blockIdx.x] = ws[0] + ws[1] + ws[2] + ws[3];
}

__global__ __launch_bounds__(1024) void k_scan_top(int* __restrict__ bsum, int nblk)
{
    __shared__ int part[1024];
    const int tid = threadIdx.x;
    int v = (tid < nblk) ? bsum[tid] : 0;
    part[tid] = v;
    __syncthreads();
    for (int d = 1; d < 1024; d <<= 1) {
        int add = (tid >= d) ? part[tid - d] : 0;
        __syncthreads();
        part[tid] += add;
        __syncthreads();
    }
    if (tid < nblk) bsum[tid] = part[tid] - v;  // exclusive
}

__global__ __launch_bounds__(256) void k_scan_out(
    const int* __restrict__ deg, const int* __restrict__ bsum,
    int* __restrict__ ptr, int nn)
{
    __shared__ int ws[4];
    const int tid = threadIdx.x;
    const int lane = tid & 63;
    const int wid = tid >> 6;
    const int base = blockIdx.x * 1024 + tid * 4;
    int4 v = make_int4(0, 0, 0, 0);
    if (base + 3 < nn) v = *(const int4*)(deg + base);
    else {
        if (base + 0 < nn) v.x = deg[base + 0];
        if (base + 1 < nn) v.y = deg[base + 1];
        if (base + 2 < nn) v.z = deg[base + 2];
    }
    int t1 = v.x + v.y, t2 = t1 + v.z;
    int total = t2 + v.w;
    int inc = total;
    #pragma unroll
    for (int off = 1; off < 64; off <<= 1) {
        int y = __shfl_up(inc, off, 64);
        if (lane >= off) inc += y;
    }
    int wexcl = inc - total;
    if (lane == 63) ws[wid] = inc;
    __syncthreads();
    int woff = 0;
    #pragma unroll
    for (int i = 0; i < 4; ++i) if (i < wid) woff += ws[i];
    int e0 = bsum[blockIdx.x] + woff + wexcl;
    int4 o;
    o.x = e0; o.y = e0 + v.x; o.z = e0 + t1; o.w = e0 + t2;
    if (base + 3 < nn) *(int4*)(ptr + base) = o;
    else {
        if (base + 0 < nn) ptr[base + 0] = o.x;
        if (base + 1 < nn) ptr[base + 1] = o.y;
        if (base + 2 < nn) ptr[base + 2] = o.z;
    }
}

__global__ __launch_bounds__(256) void k_scatter(
    const int* __restrict__ ei, int* __restrict__ ptr,
    int* __restrict__ esrc, int E)
{
    int e = blockIdx.x * 256 + threadIdx.x;
    if (e < E) {
        int pos = atomicAdd(&ptr[ei[(size_t)E + e]], 1);
        esrc[pos] = ei[e];
    }
}

// ---------------------------------------------------------------------------
// Gather + softmax + self-loop + residual + LN1 fused. Half-wave per dst.
// 4-edge software-pipelined batch: all 4 esrc, then 4 a_s, then 4 hb-row
// loads issue before any expf/FMA -> 4 gathers in flight per half-wave.
// ---------------------------------------------------------------------------
__global__ __launch_bounds__(256) void k_gather(
    const int* __restrict__ esrc, const int* __restrict__ ptr,
    const unsigned short* __restrict__ hb, const float* __restrict__ a_s,
    const float* __restrict__ a_d, const float* __restrict__ x,
    const float* __restrict__ bgat, const float* __restrict__ g1,
    const float* __restrict__ b1, unsigned short* __restrict__ h1b, int nn)
{
    int d = (blockIdx.x * 256 + threadIdx.x) >> 5;
    if (d >= nn) return;
    const int l = threadIdx.x & 31;
    const int head = l >> 2;

    const int start = (d == 0) ? 0 : ptr[d - 1];
    const int end = ptr[d];
    const float ad = a_d[(size_t)d * 8 + head];

    float4 acc = make_float4(0.f, 0.f, 0.f, 0.f);
    float wsum = 0.f;
    int e = start;
    for (; e + 4 <= end; e += 4) {
        int s0 = esrc[e + 0], s1 = esrc[e + 1], s2 = esrc[e + 2], s3 = esrc[e + 3];
        float as0 = a_s[(size_t)s0 * 8 + head];
        float as1 = a_s[(size_t)s1 * 8 + head];
        float as2 = a_s[(size_t)s2 * 8 + head];
        float as3 = a_s[(size_t)s3 * 8 + head];
        ushort4 h0 = *(const ushort4*)(hb + (size_t)s0 * 128 + 4 * l);
        ushort4 h1 = *(const ushort4*)(hb + (size_t)s1 * 128 + 4 * l);
        ushort4 h2 = *(const ushort4*)(hb + (size_t)s2 * 128 + 4 * l);
        ushort4 h3 = *(const ushort4*)(hb + (size_t)s3 * 128 + 4 * l);
        float w0 = lrelu_exp(as0 + ad);
        float w1 = lrelu_exp(as1 + ad);
        float w2 = lrelu_exp(as2 + ad);
        float w3 = lrelu_exp(as3 + ad);
        acc.x += w0 * bf2f(h0.x) + w1 * bf2f(h1.x) + w2 * bf2f(h2.x) + w3 * bf2f(h3.x);
        acc.y += w0 * bf2f(h0.y) + w1 * bf2f(h1.y) + w2 * bf2f(h2.y) + w3 * bf2f(h3.y);
        acc.z += w0 * bf2f(h0.z) + w1 * bf2f(h1.z) + w2 * bf2f(h2.z) + w3 * bf2f(h3.z);
        acc.w += w0 * bf2f(h0.w) + w1 * bf2f(h1.w) + w2 * bf2f(h2.w) + w3 * bf2f(h3.w);
        wsum += (w0 + w1) + (w2 + w3);
    }
    for (; e < end; ++e) {
        int s = esrc[e];
        float w = lrelu_exp(a_s[(size_t)s * 8 + head] + ad);
        ushort4 hv = *(const ushort4*)(hb + (size_t)s * 128 + 4 * l);
        acc.x += w * bf2f(hv.x); acc.y += w * bf2f(hv.y);
        acc.z += w * bf2f(hv.z); acc.w += w * bf2f(hv.w);
        wsum += w;
    }
    {   // self loop
        float w = lrelu_exp(a_s[(size_t)d * 8 + head] + ad);
        ushort4 hv = *(const ushort4*)(hb + (size_t)d * 128 + 4 * l);
        acc.x += w * bf2f(hv.x); acc.y += w * bf2f(hv.y);
        acc.z += w * bf2f(hv.z); acc.w += w * bf2f(hv.w);
        wsum += w;
    }
    const float inv_dn = 1.f / wsum;
    float4 xv = *(const float4*)(x + (size_t)d * 128 + 4 * l);
    float4 bg = *(const float4*)(bgat + 4 * l);
    float v0 = xv.x + acc.x * inv_dn + bg.x;
    float v1 = xv.y + acc.y * inv_dn + bg.y;
    float v2 = xv.z + acc.z * inv_dn + bg.z;
    float v3 = xv.w + acc.w * inv_dn + bg.w;

    float s = v0 + v1 + v2 + v3;
    #pragma unroll
    for (int off = 16; off; off >>= 1) s += __shfl_xor(s, off, 32);
    float mu = s * (1.f / 128.f);
    float d0 = v0 - mu, d1 = v1 - mu, d2 = v2 - mu, d3 = v3 - mu;
    float q = d0 * d0 + d1 * d1 + d2 * d2 + d3 * d3;
    #pragma unroll
    for (int off = 16; off; off >>= 1) q += __shfl_xor(q, off, 32);
    float inv = rsqrtf(q * (1.f / 128.f) + LN_EPS);

    float4 gv = ((const float4*)g1)[l];
    float4 bv = ((const float4*)b1)[l];
    ushort4 ob;
    ob.x = f2bf(d0 * inv * gv.x + bv.x);
    ob.y = f2bf(d1 * inv * gv.y + bv.y);
    ob.z = f2bf(d2 * inv * gv.z + bv.z);
    ob.w = f2bf(d3 * inv * gv.w + bv.w);
    ((ushort4*)(h1b + (size_t)d * 128))[l] = ob;
}

// ---------------------------------------------------------------------------
// Weight transpose + bf16 convert (B^T layouts for MFMA b-fragments).
// ---------------------------------------------------------------------------
__global__ __launch_bounds__(256) void k_cvt(
    const float* __restrict__ W1, const float* __restrict__ W2,
    const float* __restrict__ Wg,
    unsigned short* __restrict__ W1t, unsigned short* __restrict__ W2t,
    unsigned short* __restrict__ Wgt)
{
    int t = blockIdx.x * 256 + threadIdx.x;
    if (t < 512 * 128) {
        int n = t >> 7, k = t & 127;
        W1t[t] = f2bf(W1[(size_t)k * 512 + n]);
        int n2 = t >> 9, k2 = t & 511;
        W2t[t] = f2bf(W2[(size_t)k2 * 128 + n2]);
        if (t < 128 * 128) {
            int n3 = t >> 7, k3 = t & 127;
            Wgt[t] = f2bf(Wg[(size_t)k3 * 128 + n3]);
        }
    }
}

// ---------------------------------------------------------------------------
// FF GEMM1 (k-half p): t_p = relu(h1b @ W1[:, p*256 : p*256+256] + b1_p)
// written bf16 to th (dedicated half buffer). W1-slice LDS-resident.
// ---------------------------------------------------------------------------
__global__ __launch_bounds__(512, 4) void k_ff1(
    const unsigned short* __restrict__ h1b,
    const unsigned short* __restrict__ W1t,   // [512n][128k]
    const float* __restrict__ b1,
    unsigned short* __restrict__ th,          // [nn][256] (this half)
    int p, int nn)
{
    __shared__ __align__(16) unsigned short sw[256][136];  // 69.6 KB

    const int tid  = threadIdx.x;
    const int base = blockIdx.x * 256;
    const int lane = tid & 63;
    const int w    = tid >> 6;        // 0..7
    const int ln   = lane & 15;
    const int quad = lane >> 4;

    for (int i = tid; i < 4096; i += 512) {
        int row = i >> 4, c = i & 15;
        *(bf16x8*)&sw[row][c * 8] =
            *(const bf16x8*)(W1t + (size_t)(p * 256 + row) * 128 + c * 8);
    }
    __syncthreads();

    const bf16x8 zf = {0, 0, 0, 0, 0, 0, 0, 0};
    bf16x8 a[2][4];
    #pragma unroll
    for (int mt = 0; mt < 2; ++mt) {
        int node = base + (w * 2 + mt) * 16 + ln;
        #pragma unroll
        for (int ks = 0; ks < 4; ++ks)
            a[mt][ks] = (node < nn)
                ? *(const bf16x8*)(h1b + (size_t)node * 128 + ks * 32 + quad * 8)
                : zf;
    }

    for (int nc = 0; nc < 2; ++nc) {
        f32x4 acc[2][8];
        #pragma unroll
        for (int mt = 0; mt < 2; ++mt)
            #pragma unroll
            for (int nt = 0; nt < 8; ++nt)
                acc[mt][nt] = (f32x4){0.f, 0.f, 0.f, 0.f};

        #pragma unroll
        for (int nt = 0; nt < 8; ++nt)
            #pragma unroll
            for (int ks = 0; ks < 4; ++ks) {
                bf16x8 b = *(const bf16x8*)&sw[nc * 128 + nt * 16 + ln][ks * 32 + quad * 8];
                acc[0][nt] = __builtin_amdgcn_mfma_f32_16x16x32_bf16(a[0][ks], b, acc[0][nt], 0, 0, 0);
                acc[1][nt] = __builtin_amdgcn_mfma_f32_16x16x32_bf16(a[1][ks], b, acc[1][nt], 0, 0, 0);
            }

        #pragma unroll
        for (int nt = 0; nt < 8; ++nt) {
            int col = nc * 128 + nt * 16 + ln;
            float bb = b1[p * 256 + col];
            #pragma unroll
            for (int mt = 0; mt < 2; ++mt)
                #pragma unroll
                for (int r = 0; r < 4; ++r) {
                    int node = base + (w * 2 + mt) * 16 + quad * 4 + r;
                    if (node < nn)
                        th[(size_t)node * 256 + col] =
                            f2bf(fmaxf(acc[mt][nt][r] + bb, 0.f));
                }
        }
    }
}

// ---------------------------------------------------------------------------
// FF GEMM2, single fused dispatch over full K=512:
//   out = LN2(t @ W2 + b2 + h1).
// Full W2t in LDS (130 KB, 1 block/CU). t-halves read from th0 (= d_out,
// aliased: each wave reads only its own 32 rows before its epilogue
// overwrites them in-place -> wave-lockstep makes this safe) and th1.
// LN2 fully in-register (width-16 shuffle reduce).
// ---------------------------------------------------------------------------
__global__ __launch_bounds__(512, 2) void k_ff2f(
    const unsigned short* __restrict__ th0,   // [nn][256], k 0..255
    const unsigned short* __restrict__ th1,   // [nn][256], k 256..511
    const unsigned short* __restrict__ W2t,   // [128n][512k]
    const float* __restrict__ b2,
    const unsigned short* __restrict__ h1b,
    const float* __restrict__ g2, const float* __restrict__ bln2,
    float* __restrict__ out, int nn)
{
    __shared__ __align__(16) unsigned short sw[128][520];  // 130 KB

    const int tid  = threadIdx.x;
    const int base = blockIdx.x * 256;
    const int lane = tid & 63;
    const int w    = tid >> 6;      // 0..7 -> rows base + w*32 .. +31
    const int ln   = lane & 15;
    const int quad = lane >> 4;

    for (int i = tid; i < 8192; i += 512) {
        int row = i >> 6, c = i & 63;
        *(bf16x8*)&sw[row][c * 8] = *(const bf16x8*)(W2t + (size_t)row * 512 + c * 8);
    }
    __syncthreads();

    const bf16x8 zf = {0, 0, 0, 0, 0, 0, 0, 0};
    const int node0 = base + w * 32 + ln;
    const int node1 = node0 + 16;

    f32x4 acc[2][8];
    #pragma unroll
    for (int mt = 0; mt < 2; ++mt)
        #pragma unroll
        for (int nt = 0; nt < 8; ++nt)
            acc[mt][nt] = (f32x4){0.f, 0.f, 0.f, 0.f};

    #pragma unroll
    for (int half = 0; half < 2; ++half) {
        const unsigned short* th = half ? th1 : th0;
        for (int ks = 0; ks < 8; ++ks) {
            bf16x8 a0 = (node0 < nn)
                ? *(const bf16x8*)(th + (size_t)node0 * 256 + ks * 32 + quad * 8) : zf;
            bf16x8 a1 = (node1 < nn)
                ? *(const bf16x8*)(th + (size_t)node1 * 256 + ks * 32 + quad * 8) : zf;
            #pragma unroll
            for (int nt = 0; nt < 8; ++nt) {
                bf16x8 b = *(const bf16x8*)&sw[nt * 16 + ln][half * 256 + ks * 32 + quad * 8];
                acc[0][nt] = __builtin_amdgcn_mfma_f32_16x16x32_bf16(a0, b, acc[0][nt], 0, 0, 0);
                acc[1][nt] = __builtin_amdgcn_mfma_f32_16x16x32_bf16(a1, b, acc[1][nt], 0, 0, 0);
            }
        }
    }

    float gv[8], bv[8], bb[8];
    #pragma unroll
    for (int nt = 0; nt < 8; ++nt) {
        int col = nt * 16 + ln;
        gv[nt] = g2[col]; bv[nt] = bln2[col]; bb[nt] = b2[col];
    }
    #pragma unroll
    for (int mt = 0; mt < 2; ++mt) {
        #pragma unroll
        for (int r = 0; r < 4; ++r) {
            int node = base + w * 32 + mt * 16 + quad * 4 + r;
            bool ok = node < nn;
            float v[8];
            #pragma unroll
            for (int nt = 0; nt < 8; ++nt) {
                int col = nt * 16 + ln;
                float res = ok ? bf2f(h1b[(size_t)node * 128 + col]) : 0.f;
                v[nt] = acc[mt][nt][r] + bb[nt] + res;
            }
            float s = 0.f;
            #pragma unroll
            for (int nt = 0; nt < 8; ++nt) s += v[nt];
            #pragma unroll
            for (int off = 1; off < 16; off <<= 1) s += __shfl_xor(s, off, 16);
            float mu = s * (1.f / 128.f);
            float q = 0.f;
            #pragma unroll
            for (int nt = 0; nt < 8; ++nt) { float dd = v[nt] - mu; q += dd * dd; }
            #pragma unroll
            for (int off = 1; off < 16; off <<= 1) q += __shfl_xor(q, off, 16);
            float inv = rsqrtf(q * (1.f / 128.f) + LN_EPS);
            if (ok)
                #pragma unroll
                for (int nt = 0; nt < 8; ++nt) {
                    int col = nt * 16 + ln;
                    out[(size_t)node * 128 + col] = (v[nt] - mu) * inv * gv[nt] + bv[nt];
                }
        }
    }
}

// ---------------------------------------------------------------------------
extern "C" void kernel_launch(void* const* d_in, const int* in_sizes, int n_in,
                              void* d_out, int out_size, void* d_ws, size_t ws_size,
                              hipStream_t stream) {
    const float* x    = (const float*)d_in[0];
    const int*   ei   = (const int*)d_in[1];
    const float* Wg   = (const float*)d_in[2];
    const float* atts = (const float*)d_in[3];
    const float* attd = (const float*)d_in[4];
    const float* bgat = (const float*)d_in[5];
    const float* W1   = (const float*)d_in[6];
    const float* b1   = (const float*)d_in[7];
    const float* W2   = (const float*)d_in[8];
    const float* b2   = (const float*)d_in[9];
    const float* g1   = (const float*)d_in[10];
    const float* bln1 = (const float*)d_in[11];
    const float* g2   = (const float*)d_in[12];
    const float* bln2 = (const float*)d_in[13];
    float* out = (float*)d_out;

    const int nn = in_sizes[0] / 128;
    const int E  = in_sizes[1] / 2;
    const int nblk = (nn + 1023) / 1024;

    // workspace: W1t | W2t | Wgt | h1b | region{ phase1: hb|a_s|a_d|deg|ptr|bsum|esrc
    //                                            phase2: th1 (nn*256 bf16) }  ~77 MB
    // th0 (nn*256 bf16 = nn*128 fp32 bytes) lives in d_out until k_ff2f.
    uintptr_t pa = ((uintptr_t)d_ws + 15) & ~(uintptr_t)15;
    unsigned short* W1t = (unsigned short*)pa;
    unsigned short* W2t = W1t + 512 * 128;
    unsigned short* Wgt = W2t + 128 * 512;
    unsigned short* h1b = Wgt + 128 * 128;
    unsigned short* region = h1b + (size_t)nn * 128;
    // phase-1 view
    unsigned short* hb = region;
    float* a_s = (float*)(hb + (size_t)nn * 128);
    float* a_d = a_s + (size_t)nn * 8;
    int*   deg = (int*)(a_d + (size_t)nn * 8);
    int*   ptr = deg + nn;
    int*   bsum = ptr + nn;
    int*   esrc = bsum + 1024;
    // phase-2 view (aliases phase-1)
    unsigned short* th1 = region;
    unsigned short* th0 = (unsigned short*)d_out;

    hipMemsetAsync(deg, 0, (size_t)nn * sizeof(int), stream);

    k_cvt<<<dim3(256), dim3(256), 0, stream>>>(W1, W2, Wg, W1t, W2t, Wgt);
    k_gat_projm<<<dim3((nn + 63) / 64), dim3(256), 0, stream>>>(
        x, Wgt, atts, attd, hb, a_s, a_d, nn);
    k_deg<<<dim3((E + 255) / 256), dim3(256), 0, stream>>>(ei, deg, E);
    k_scan_blk<<<dim3(nblk), dim3(256), 0, stream>>>(deg, bsum, nn);
    k_scan_top<<<dim3(1), dim3(1024), 0, stream>>>(bsum, nblk);
    k_scan_out<<<dim3(nblk), dim3(256), 0, stream>>>(deg, bsum, ptr, nn);
    k_scatter<<<dim3((E + 255) / 256), dim3(256), 0, stream>>>(ei, ptr, esrc, E);
    k_gather<<<dim3((nn * 32 + 255) / 256), dim3(256), 0, stream>>>(
        esrc, ptr, hb, a_s, a_d, x, bgat, g1, bln1, h1b, nn);

    const int gff = (nn + 255) / 256;
    k_ff1<<<dim3(gff), dim3(512), 0, stream>>>(h1b, W1t, b1, th0, 0, nn);
    k_ff1<<<dim3(gff), dim3(512), 0, stream>>>(h1b, W1t, b1, th1, 1, nn);
    k_ff2f<<<dim3(gff), dim3(512), 0, stream>>>(
        th0, th1, W2t, b2, h1b, g2, bln2, out, nn);
}